// Round 1
// 812.169 us; speedup vs baseline: 1.0290x; 1.0290x over previous
//
#include <hip/hip_runtime.h>
#include <math.h>

typedef unsigned short ushort_t;
typedef __bf16 bf16x8 __attribute__((ext_vector_type(8)));
typedef float f32x4 __attribute__((ext_vector_type(4)));

#define BB 16
#define TT 512
#define DD 1024
#define HH 16
#define DKK 64
#define WIN 128
#define MAXLEN 512

#define TILE_M 64
#define JSPAN 320
#define NCHUNK 5
#define LSTR 68

#define BK 32   // K-step in ushorts; LDS rows are 64B, linear (global_load_lds-compatible)

// async global->LDS, 16B per lane, wave-uniform LDS base + lane*16 (m97 staging path)
#define GLOAD16(g, l)                                                                              \
    __builtin_amdgcn_global_load_lds((const __attribute__((address_space(1))) unsigned int*)(g),   \
                                     (__attribute__((address_space(3))) unsigned int*)(l), 16, 0, 0)

// ---------------- fp32 -> bf16 hi/lo split helpers ----------------
__device__ __forceinline__ ushort_t f2bf(float f) {
    union { float f; unsigned u; } x; x.f = f;
    unsigned r = x.u + 0x7fffu + ((x.u >> 16) & 1u);   // RTN-even
    return (ushort_t)(r >> 16);
}
__device__ __forceinline__ float bf2f(ushort_t h) {
    union { unsigned u; float f; } x; x.u = ((unsigned)h) << 16;
    return x.f;
}

// ---------------- conversion: A [M][K] fp32 -> hi/lo bf16 same layout ----------------
__global__ __launch_bounds__(256) void conv_split(const float* __restrict__ src,
                                                  ushort_t* __restrict__ hi,
                                                  ushort_t* __restrict__ lo, int n4)
{
    const int i = blockIdx.x * 256 + threadIdx.x;
    if (i >= n4) return;
    float4 vf = ((const float4*)src)[i];
    ushort_t h0 = f2bf(vf.x), h1 = f2bf(vf.y), h2 = f2bf(vf.z), h3 = f2bf(vf.w);
    ushort4 hv = make_ushort4(h0, h1, h2, h3);
    ushort4 lv = make_ushort4(f2bf(vf.x - bf2f(h0)), f2bf(vf.y - bf2f(h1)),
                              f2bf(vf.z - bf2f(h2)), f2bf(vf.w - bf2f(h3)));
    ((ushort4*)hi)[i] = hv;
    ((ushort4*)lo)[i] = lv;
}

// ---------------- conversion + transpose: W [K][N] fp32 -> [N][K] hi/lo bf16 ----------------
__global__ __launch_bounds__(256) void conv_split_T(const float* __restrict__ W,
                                                    ushort_t* __restrict__ hiT,
                                                    ushort_t* __restrict__ loT,
                                                    int K, int N)
{
    __shared__ ushort_t th[32][33], tl[32][33];
    const int n0 = blockIdx.x * 32, k0 = blockIdx.y * 32;
    const int tid = threadIdx.x;
    const int r = tid >> 3, c4 = (tid & 7) * 4;
    float4 vf = *(const float4*)&W[(size_t)(k0 + r) * N + n0 + c4];
    float vv[4] = {vf.x, vf.y, vf.z, vf.w};
#pragma unroll
    for (int j = 0; j < 4; ++j) {
        ushort_t h = f2bf(vv[j]);
        th[r][c4 + j] = h;
        tl[r][c4 + j] = f2bf(vv[j] - bf2f(h));
    }
    __syncthreads();
    ushort4 oh = make_ushort4(th[c4 + 0][r], th[c4 + 1][r], th[c4 + 2][r], th[c4 + 3][r]);
    ushort4 ol = make_ushort4(tl[c4 + 0][r], tl[c4 + 1][r], tl[c4 + 2][r], tl[c4 + 3][r]);
    *(ushort4*)&hiT[(size_t)(n0 + r) * K + k0 + c4] = oh;
    *(ushort4*)&loT[(size_t)(n0 + r) * K + k0 + c4] = ol;
}

// ---------------- split-bf16 MFMA mainloop: C[128][128] += A[128][K] * B^T[128][K]^T ----------------
// m97 structure: linear [128][BK] LDS tiles staged via global_load_lds (16B/lane),
// 2-barrier single-buffer K-loop. Bank-conflict fix per rule #21: LDS dest stays linear,
// the per-lane GLOBAL source is inverse-swizzled and the ds_read address applies the same
// XOR: slot q' = q ^ ((row>>1)&3). This spreads 16 consecutive rows (64B stride) across all
// eight 16B bank groups -> 2 lanes/group per 16-lane phase = conflict-free (m136).
// A-frag: lane holds A[m=lane&15][k=quad*8+j]; B-frag: B[k=quad*8+j][n=lane&15]
// (B stored transposed [n][k] so both use identical contiguous-k addressing)
// C/D: col=lane&15, row=quad*4+reg  [verified m89/m91]
__device__ __forceinline__ void mfma_mainloop(const ushort_t* __restrict__ Ah,
                                              const ushort_t* __restrict__ Al,
                                              const ushort_t* __restrict__ Bh,
                                              const ushort_t* __restrict__ Bl,
                                              int K, int m0, int n0,
                                              ushort_t* smem, f32x4 (&acc)[4][4])
{
    ushort_t* sAh = smem;
    ushort_t* sAl = smem + 128 * BK;
    ushort_t* sBh = smem + 2 * 128 * BK;
    ushort_t* sBl = smem + 3 * 128 * BK;
    const int tid = threadIdx.x;
    const int lane = tid & 63;
    const int w = tid >> 6;
    const int wm = (w >> 1) * 64, wn = (w & 1) * 64;
    const int c16 = lane & 15;
    const int quad = lane >> 4;

    // ---- staging descriptors: each wave stages rows [w*32, w*32+32) of each tensor ----
    // one global_load_lds covers 16 rows (64 lanes * 16B = 1024B); lane l -> (row=l>>2, slot=l&3)
    const int lrow = lane >> 2, lq = lane & 3;
    const int r0 = w * 32, r1 = w * 32 + 16;
    const int row0 = r0 + lrow, row1 = r1 + lrow;
    const int qd0 = lq ^ ((row0 >> 1) & 3);          // inverse swizzle (XOR is an involution)
    const int qd1 = lq ^ ((row1 >> 1) & 3);
    const size_t a0 = (size_t)(m0 + row0) * K + qd0 * 8;
    const size_t a1 = (size_t)(m0 + row1) * K + qd1 * 8;
    const size_t b0 = (size_t)(n0 + row0) * K + qd0 * 8;
    const size_t b1 = (size_t)(n0 + row1) * K + qd1 * 8;
    char* dAh0 = (char*)sAh + r0 * 64;  char* dAh1 = (char*)sAh + r1 * 64;
    char* dAl0 = (char*)sAl + r0 * 64;  char* dAl1 = (char*)sAl + r1 * 64;
    char* dBh0 = (char*)sBh + r0 * 64;  char* dBh1 = (char*)sBh + r1 * 64;
    char* dBl0 = (char*)sBl + r0 * 64;  char* dBl1 = (char*)sBl + r1 * 64;

    // ---- swizzled ds_read offsets (ushort units), constant over the K-loop ----
    int aoff[4], boff[4];
#pragma unroll
    for (int mt = 0; mt < 4; ++mt) {
        const int row = wm + mt * 16 + c16;
        aoff[mt] = row * BK + ((quad ^ ((row >> 1) & 3)) * 8);
    }
#pragma unroll
    for (int nt = 0; nt < 4; ++nt) {
        const int row = wn + nt * 16 + c16;
        boff[nt] = row * BK + ((quad ^ ((row >> 1) & 3)) * 8);
    }

    for (int k0 = 0; k0 < K; k0 += BK) {
        __syncthreads();                 // all waves done reading previous tile (lgkm drained at barrier)
        GLOAD16(Ah + a0 + k0, dAh0);
        GLOAD16(Ah + a1 + k0, dAh1);
        GLOAD16(Al + a0 + k0, dAl0);
        GLOAD16(Al + a1 + k0, dAl1);
        GLOAD16(Bh + b0 + k0, dBh0);
        GLOAD16(Bh + b1 + k0, dBh1);
        GLOAD16(Bl + b0 + k0, dBl0);
        GLOAD16(Bl + b1 + k0, dBl1);
        __syncthreads();                 // vmcnt(0) drained before barrier -> tile resident

        bf16x8 ah[4], al[4];
#pragma unroll
        for (int mt = 0; mt < 4; ++mt) {
            ah[mt] = *(const bf16x8*)&sAh[aoff[mt]];
            al[mt] = *(const bf16x8*)&sAl[aoff[mt]];
        }
#pragma unroll
        for (int nt = 0; nt < 4; ++nt) {
            bf16x8 bh = *(const bf16x8*)&sBh[boff[nt]];
            bf16x8 bl = *(const bf16x8*)&sBl[boff[nt]];
#pragma unroll
            for (int mt = 0; mt < 4; ++mt) {
                acc[mt][nt] = __builtin_amdgcn_mfma_f32_16x16x32_bf16(ah[mt], bh, acc[mt][nt], 0, 0, 0);
                acc[mt][nt] = __builtin_amdgcn_mfma_f32_16x16x32_bf16(al[mt], bh, acc[mt][nt], 0, 0, 0);
                acc[mt][nt] = __builtin_amdgcn_mfma_f32_16x16x32_bf16(ah[mt], bl, acc[mt][nt], 0, 0, 0);
            }
        }
    }
}

// ---------------- GEMM 1: qkv = x @ Wqkv + bqkv -> scatter q,k,v [B,H,T,DK] ----------------
__global__ __launch_bounds__(256) void qkv_mfma(const ushort_t* __restrict__ xh,
                                                const ushort_t* __restrict__ xl,
                                                const ushort_t* __restrict__ wh,
                                                const ushort_t* __restrict__ wl,
                                                const float* __restrict__ bias,
                                                float* __restrict__ q,
                                                float* __restrict__ k,
                                                float* __restrict__ v)
{
    __shared__ ushort_t smem[4 * 128 * BK];
    f32x4 acc[4][4] = {};
    const int m0 = blockIdx.y * 128, n0 = blockIdx.x * 128;
    mfma_mainloop(xh, xl, wh, wl, DD, m0, n0, smem, acc);

    const int tid = threadIdx.x, lane = tid & 63, w = tid >> 6;
    const int wm = (w >> 1) * 64, wn = (w & 1) * 64;
    const int c16 = lane & 15, rq = (lane >> 4) * 4;
#pragma unroll
    for (int mt = 0; mt < 4; ++mt)
#pragma unroll
        for (int nt = 0; nt < 4; ++nt)
#pragma unroll
            for (int r = 0; r < 4; ++r) {
                const int m = m0 + wm + mt * 16 + rq + r;
                const int n = n0 + wn + nt * 16 + c16;
                const float val = acc[mt][nt][r] + bias[n];
                const int bidx = m >> 9, t = m & (TT - 1);
                const int sel = n >> 10, d = n & (DD - 1);
                const int h = d >> 6, dk = d & (DKK - 1);
                float* dst = (sel == 0) ? q : (sel == 1) ? k : v;
                dst[((((size_t)bidx * HH + h) * TT + t) * DKK) + dk] = val;
            }
}

// ---------------- GEMM 2: out = ctx @ Wo + bo ----------------
__global__ __launch_bounds__(256) void out_mfma(const ushort_t* __restrict__ ah,
                                                const ushort_t* __restrict__ al,
                                                const ushort_t* __restrict__ wh,
                                                const ushort_t* __restrict__ wl,
                                                const float* __restrict__ bias,
                                                float* __restrict__ out)
{
    __shared__ ushort_t smem[4 * 128 * BK];
    f32x4 acc[4][4] = {};
    const int m0 = blockIdx.y * 128, n0 = blockIdx.x * 128;
    mfma_mainloop(ah, al, wh, wl, DD, m0, n0, smem, acc);

    const int tid = threadIdx.x, lane = tid & 63, w = tid >> 6;
    const int wm = (w >> 1) * 64, wn = (w & 1) * 64;
    const int c16 = lane & 15, rq = (lane >> 4) * 4;
#pragma unroll
    for (int mt = 0; mt < 4; ++mt)
#pragma unroll
        for (int nt = 0; nt < 4; ++nt)
#pragma unroll
            for (int r = 0; r < 4; ++r) {
                const int m = m0 + wm + mt * 16 + rq + r;
                const int n = n0 + wn + nt * 16 + c16;
                out[(size_t)m * DD + n] = acc[mt][nt][r] + bias[n];
            }
}

// ---------------- Fused windowed attention, flash-style, 64-row tiles ----------------
__global__ __launch_bounds__(256) void attn_fused(const float* __restrict__ q,
                                                  const float* __restrict__ k,
                                                  const float* __restrict__ v,
                                                  const float* __restrict__ rel,
                                                  float* __restrict__ attn_out,
                                                  float* __restrict__ ctx)
{
    const int it = blockIdx.x;
    const int h  = blockIdx.y;
    const int b  = blockIdx.z;
    const int i0 = it * TILE_M;
    int jbase = i0 - WIN; if (jbase < 0) jbase = 0; if (jbase > TT - JSPAN) jbase = TT - JSPAN;

    const int tid = threadIdx.x;
    const int tx = tid & 15, ty = tid >> 4;

    __shared__ float smem[2 * TILE_M * LSTR + 1024];
    float* buf0   = smem;
    float* buf1   = smem + TILE_M * LSTR;
    float* bias_s = smem + 2 * TILE_M * LSTR;

    const size_t bh = (size_t)b * HH + h;
    const float* qb = q + (bh * TT + i0) * DKK;
    const float* kb = k + bh * TT * DKK;
    const float* vb = v + bh * TT * DKK;
    float* arow = attn_out + (bh * TT + i0) * TT;

    {
        const float4 z = make_float4(0.f, 0.f, 0.f, 0.f);
        for (int idx = tid; idx < TILE_M * 48; idx += 256) {
            const int r  = idx / 48;
            const int c4 = idx - r * 48;
            const int col = (c4 * 4 < jbase) ? c4 * 4 : c4 * 4 + JSPAN;
            *(float4*)&arow[(size_t)r * TT + col] = z;
        }
    }

    for (int idx = tid; idx < 2 * MAXLEN - 1; idx += 256)
        bias_s[idx] = rel[(size_t)idx * HH + h];

    {
        const int d = tid & 63, r0 = tid >> 6;
#pragma unroll
        for (int ii = 0; ii < 16; ++ii) {
            const int i = r0 + ii * 4;
            buf0[d * LSTR + i] = qb[(size_t)i * DKK + d];
        }
    }
    __syncthreads();

    float s[NCHUNK][4][4];
#pragma unroll 1
    for (int c = 0; c < NCHUNK; ++c) {
        if (c > 0) __syncthreads();
        {
            const int d = tid & 63, r0 = tid >> 6;
#pragma unroll
            for (int jj = 0; jj < 16; ++jj) {
                const int j = r0 + jj * 4;
                buf1[d * LSTR + j] = kb[(size_t)(jbase + c * 64 + j) * DKK + d];
            }
        }
        __syncthreads();
        float acc[4][4] = {};
#pragma unroll
        for (int kk = 0; kk < 64; ++kk) {
            float4 a  = *(const float4*)&buf0[kk * LSTR + ty * 4];
            float4 b4 = *(const float4*)&buf1[kk * LSTR + tx * 4];
            float av[4] = {a.x, a.y, a.z, a.w};
            float bv[4] = {b4.x, b4.y, b4.z, b4.w};
#pragma unroll
            for (int r = 0; r < 4; ++r)
#pragma unroll
                for (int ccx = 0; ccx < 4; ++ccx)
                    acc[r][ccx] += av[r] * bv[ccx];
        }
#pragma unroll
        for (int r = 0; r < 4; ++r) {
            const int i = i0 + ty * 4 + r;
#pragma unroll
            for (int ccx = 0; ccx < 4; ++ccx) {
                const int j = jbase + c * 64 + tx * 4 + ccx;
                const int d = j - i;
                const float val = acc[r][ccx] * 0.125f + bias_s[d + MAXLEN - 1];
                s[c][r][ccx] = (d >= -WIN && d <= WIN) ? val : -INFINITY;
            }
        }
    }

    float mrow[4], sumr[4];
#pragma unroll
    for (int r = 0; r < 4; ++r) {
        float m = -INFINITY;
#pragma unroll
        for (int c = 0; c < NCHUNK; ++c)
#pragma unroll
            for (int ccx = 0; ccx < 4; ++ccx) m = fmaxf(m, s[c][r][ccx]);
        mrow[r] = m;
    }
#pragma unroll
    for (int off = 1; off < 16; off <<= 1)
#pragma unroll
        for (int r = 0; r < 4; ++r)
            mrow[r] = fmaxf(mrow[r], __shfl_xor(mrow[r], off));
#pragma unroll
    for (int r = 0; r < 4; ++r) sumr[r] = 0.f;
#pragma unroll
    for (int c = 0; c < NCHUNK; ++c)
#pragma unroll
        for (int r = 0; r < 4; ++r)
#pragma unroll
            for (int ccx = 0; ccx < 4; ++ccx) {
                const float e = __expf(s[c][r][ccx] - mrow[r]);
                s[c][r][ccx] = e;
                sumr[r] += e;
            }
#pragma unroll
    for (int off = 1; off < 16; off <<= 1)
#pragma unroll
        for (int r = 0; r < 4; ++r)
            sumr[r] += __shfl_xor(sumr[r], off);
    float invr[4];
#pragma unroll
    for (int r = 0; r < 4; ++r) invr[r] = 1.0f / sumr[r];
#pragma unroll
    for (int c = 0; c < NCHUNK; ++c)
#pragma unroll
        for (int r = 0; r < 4; ++r)
#pragma unroll
            for (int ccx = 0; ccx < 4; ++ccx)
                s[c][r][ccx] *= invr[r];

    float o[4][4] = {};
#pragma unroll 1
    for (int c = 0; c < NCHUNK; ++c) {
        __syncthreads();
#pragma unroll
        for (int r = 0; r < 4; ++r) {
            float4 pv = make_float4(s[c][r][0], s[c][r][1], s[c][r][2], s[c][r][3]);
            *(float4*)&arow[(size_t)(ty * 4 + r) * TT + jbase + c * 64 + tx * 4] = pv;
#pragma unroll
            for (int ccx = 0; ccx < 4; ++ccx)
                buf0[(tx * 4 + ccx) * LSTR + ty * 4 + r] = s[c][r][ccx];
        }
        {
            const int d4 = (tid & 15) * 4, r0 = tid >> 4;
#pragma unroll
            for (int jj = 0; jj < 4; ++jj) {
                const int j = r0 + jj * 16;
                *(float4*)&buf1[j * LSTR + d4] =
                    *(const float4*)&vb[(size_t)(jbase + c * 64 + j) * DKK + d4];
            }
        }
        __syncthreads();
#pragma unroll
        for (int kk = 0; kk < 64; ++kk) {
            float4 a  = *(const float4*)&buf0[kk * LSTR + ty * 4];
            float4 b4 = *(const float4*)&buf1[kk * LSTR + tx * 4];
            float av[4] = {a.x, a.y, a.z, a.w};
            float bv[4] = {b4.x, b4.y, b4.z, b4.w};
#pragma unroll
            for (int r = 0; r < 4; ++r)
#pragma unroll
                for (int ccx = 0; ccx < 4; ++ccx)
                    o[r][ccx] += av[r] * bv[ccx];
        }
    }

#pragma unroll
    for (int r = 0; r < 4; ++r) {
        float4 ov = make_float4(o[r][0], o[r][1], o[r][2], o[r][3]);
        *(float4*)&ctx[(((size_t)b * TT + i0 + ty * 4 + r) * HH + h) * DKK + tx * 4] = ov;
    }
}

extern "C" void kernel_launch(void* const* d_in, const int* in_sizes, int n_in,
                              void* d_out, int out_size, void* d_ws, size_t ws_size,
                              hipStream_t stream)
{
    const float* x    = (const float*)d_in[0];
    const float* Wqkv = (const float*)d_in[1];
    const float* bqkv = (const float*)d_in[2];
    const float* Wo   = (const float*)d_in[3];
    const float* bo   = (const float*)d_in[4];
    const float* rel  = (const float*)d_in[5];

    float* out  = (float*)d_out;
    float* attn = out + (size_t)BB * TT * DD;

    const size_t per = (size_t)BB * HH * TT * DKK;   // 8,388,608
    float* q = (float*)d_ws;
    float* k = q + per;
    float* v = k + per;
    ushort_t* xh = (ushort_t*)(v + per);
    ushort_t* xl = xh + per;
    float* ctx = (float*)xh;                 // aliases xh/xl (dead after qkv_mfma)
    ushort_t* Wqh = (ushort_t*)(xl + per);
    ushort_t* Wql = Wqh + (size_t)DD * 3 * DD;
    ushort_t* cxh = (ushort_t*)q;            // aliases q (dead after attn)
    ushort_t* cxl = (ushort_t*)k;            // aliases k (dead after attn)
    ushort_t* Woh = (ushort_t*)v;            // aliases v (dead after attn)
    ushort_t* Wol = Woh + (size_t)DD * DD;

    const int n4x = BB * TT * DD / 4;        // 2,097,152

    conv_split<<<dim3((n4x + 255) / 256), 256, 0, stream>>>(x, xh, xl, n4x);
    conv_split_T<<<dim3(3 * DD / 32, DD / 32), 256, 0, stream>>>(Wqkv, Wqh, Wql, DD, 3 * DD);
    qkv_mfma<<<dim3(3 * DD / 128, BB * TT / 128), 256, 0, stream>>>(xh, xl, Wqh, Wql, bqkv, q, k, v);
    attn_fused<<<dim3(TT / TILE_M, HH, BB), 256, 0, stream>>>(q, k, v, rel, attn, ctx);
    conv_split<<<dim3((n4x + 255) / 256), 256, 0, stream>>>(ctx, cxh, cxl, n4x);
    conv_split_T<<<dim3(DD / 32, DD / 32), 256, 0, stream>>>(Wo, Woh, Wol, DD, DD);
    out_mfma<<<dim3(DD / 128, BB * TT / 128), 256, 0, stream>>>(cxh, cxl, Woh, Wol, bo, out);
}

// Round 3
// 794.976 us; speedup vs baseline: 1.0513x; 1.0216x over previous
//
#include <hip/hip_runtime.h>
#include <math.h>

typedef unsigned short ushort_t;
typedef __bf16 bf16x8 __attribute__((ext_vector_type(8)));
typedef float f32x4 __attribute__((ext_vector_type(4)));

#define BB 16
#define TT 512
#define DD 1024
#define HH 16
#define DKK 64
#define WIN 128
#define MAXLEN 512

#define TILE_M 64
#define JSPAN 320
#define NCHUNK 5
#define LSTR 68

#define BK 32                 // K-step in ushorts; LDS rows 64B, linear
#define TBUF (128 * BK)       // ushorts per tensor per buffer
#define BUFU (4 * TBUF)       // ushorts per buffer (4 tensors)
#define KSTEPS (DD / BK)      // 32

// async global->LDS, 16B per lane, wave-uniform LDS base + lane*16
#define GLOAD16(g, l)                                                                              \
    __builtin_amdgcn_global_load_lds((const __attribute__((address_space(1))) unsigned int*)(g),   \
                                     (__attribute__((address_space(3))) unsigned int*)(l), 16, 0, 0)

// ---------------- fp32 -> bf16 hi/lo split helpers ----------------
__device__ __forceinline__ ushort_t f2bf(float f) {
    union { float f; unsigned u; } x; x.f = f;
    unsigned r = x.u + 0x7fffu + ((x.u >> 16) & 1u);   // RTN-even
    return (ushort_t)(r >> 16);
}
__device__ __forceinline__ float bf2f(ushort_t h) {
    union { unsigned u; float f; } x; x.u = ((unsigned)h) << 16;
    return x.f;
}

// ---------------- conversion: A [M][K] fp32 -> hi/lo bf16 same layout ----------------
__global__ __launch_bounds__(256) void conv_split(const float* __restrict__ src,
                                                  ushort_t* __restrict__ hi,
                                                  ushort_t* __restrict__ lo, int n4)
{
    const int i = blockIdx.x * 256 + threadIdx.x;
    if (i >= n4) return;
    float4 vf = ((const float4*)src)[i];
    ushort_t h0 = f2bf(vf.x), h1 = f2bf(vf.y), h2 = f2bf(vf.z), h3 = f2bf(vf.w);
    ushort4 hv = make_ushort4(h0, h1, h2, h3);
    ushort4 lv = make_ushort4(f2bf(vf.x - bf2f(h0)), f2bf(vf.y - bf2f(h1)),
                              f2bf(vf.z - bf2f(h2)), f2bf(vf.w - bf2f(h3)));
    ((ushort4*)hi)[i] = hv;
    ((ushort4*)lo)[i] = lv;
}

// ---------------- conversion + transpose: W [K][N] fp32 -> [N][K] hi/lo bf16 ----------------
__global__ __launch_bounds__(256) void conv_split_T(const float* __restrict__ W,
                                                    ushort_t* __restrict__ hiT,
                                                    ushort_t* __restrict__ loT,
                                                    int K, int N)
{
    __shared__ ushort_t th[32][33], tl[32][33];
    const int n0 = blockIdx.x * 32, k0 = blockIdx.y * 32;
    const int tid = threadIdx.x;
    const int r = tid >> 3, c4 = (tid & 7) * 4;
    float4 vf = *(const float4*)&W[(size_t)(k0 + r) * N + n0 + c4];
    float vv[4] = {vf.x, vf.y, vf.z, vf.w};
#pragma unroll
    for (int j = 0; j < 4; ++j) {
        ushort_t h = f2bf(vv[j]);
        th[r][c4 + j] = h;
        tl[r][c4 + j] = f2bf(vv[j] - bf2f(h));
    }
    __syncthreads();
    ushort4 oh = make_ushort4(th[c4 + 0][r], th[c4 + 1][r], th[c4 + 2][r], th[c4 + 3][r]);
    ushort4 ol = make_ushort4(tl[c4 + 0][r], tl[c4 + 1][r], tl[c4 + 2][r], tl[c4 + 3][r]);
    *(ushort4*)&hiT[(size_t)(n0 + r) * K + k0 + c4] = oh;
    *(ushort4*)&loT[(size_t)(n0 + r) * K + k0 + c4] = ol;
}

// ---------------- split-bf16 MFMA mainloop, 2-phase double-buffered ----------------
// T3-minimum schedule (catalog): issue next tile's 8 global_load_lds BEFORE computing the
// current tile; counted s_waitcnt vmcnt(8) (the 8 in-flight next-tile loads stay pending);
// raw s_barrier (NOT __syncthreads -> no vmcnt(0) drain). Two 32KB buffers.
// Bank-conflict fix per rule #21 unchanged: linear LDS dest, inverse-swizzled global source,
// same XOR on ds_read: slot q' = q ^ ((row>>1)&3)  -> 2 lanes/bank = free (m136).
// A-frag: lane holds A[m=lane&15][k=quad*8+j]; B-frag: B[k=quad*8+j][n=lane&15]
// C/D: col=lane&15, row=quad*4+reg  [verified m89/m91]
__device__ __forceinline__ void mfma_mainloop(const ushort_t* __restrict__ Ah,
                                              const ushort_t* __restrict__ Al,
                                              const ushort_t* __restrict__ Bh,
                                              const ushort_t* __restrict__ Bl,
                                              int m0, int n0,
                                              ushort_t* smem, f32x4 (&acc)[4][4])
{
    const int tid = threadIdx.x;
    const int lane = tid & 63;
    const int w = tid >> 6;
    const int wm = (w >> 1) * 64, wn = (w & 1) * 64;
    const int c16 = lane & 15;
    const int quad = lane >> 4;

    // staging: wave w stages rows [w*32, w*32+32) of each tensor; one GLOAD16 = 16 rows
    const int lrow = lane >> 2, lq = lane & 3;
    const int r0 = w * 32, r1 = w * 32 + 16;
    const int row0 = r0 + lrow, row1 = r1 + lrow;
    const int qd0 = lq ^ ((row0 >> 1) & 3);          // inverse swizzle (XOR involution)
    const int qd1 = lq ^ ((row1 >> 1) & 3);
    const size_t a0 = (size_t)(m0 + row0) * DD + qd0 * 8;
    const size_t a1 = (size_t)(m0 + row1) * DD + qd1 * 8;
    const size_t b0 = (size_t)(n0 + row0) * DD + qd0 * 8;
    const size_t b1 = (size_t)(n0 + row1) * DD + qd1 * 8;

    auto STAGE = [&](int buf, int k0) {
        ushort_t* s_ = smem + buf * BUFU;
        GLOAD16(Ah + a0 + k0, (char*)s_ + r0 * 64);
        GLOAD16(Ah + a1 + k0, (char*)s_ + r1 * 64);
        GLOAD16(Al + a0 + k0, (char*)(s_ + TBUF) + r0 * 64);
        GLOAD16(Al + a1 + k0, (char*)(s_ + TBUF) + r1 * 64);
        GLOAD16(Bh + b0 + k0, (char*)(s_ + 2 * TBUF) + r0 * 64);
        GLOAD16(Bh + b1 + k0, (char*)(s_ + 2 * TBUF) + r1 * 64);
        GLOAD16(Bl + b0 + k0, (char*)(s_ + 3 * TBUF) + r0 * 64);
        GLOAD16(Bl + b1 + k0, (char*)(s_ + 3 * TBUF) + r1 * 64);
    };

    // swizzled ds_read offsets (ushort units), constant over the K-loop
    int aoff[4], boff[4];
#pragma unroll
    for (int mt = 0; mt < 4; ++mt) {
        const int row = wm + mt * 16 + c16;
        aoff[mt] = row * BK + ((quad ^ ((row >> 1) & 3)) * 8);
    }
#pragma unroll
    for (int nt = 0; nt < 4; ++nt) {
        const int row = wn + nt * 16 + c16;
        boff[nt] = row * BK + ((quad ^ ((row >> 1) & 3)) * 8);
    }

    STAGE(0, 0);                                     // prologue: tile 0 in flight (8 loads)
    for (int t = 0; t < KSTEPS; ++t) {
        const int cur = t & 1;
        if (t + 1 < KSTEPS) {
            STAGE(cur ^ 1, (t + 1) * BK);            // 16 outstanding now
            asm volatile("s_waitcnt vmcnt(8)" ::: "memory");   // tile t resident; next 8 in flight
        } else {
            asm volatile("s_waitcnt vmcnt(0)" ::: "memory");
        }
        __builtin_amdgcn_sched_barrier(0);
        __builtin_amdgcn_s_barrier();                // all waves' tile-t data visible

        const ushort_t* sAh = smem + cur * BUFU;
        const ushort_t* sAl = sAh + TBUF;
        const ushort_t* sBh = sAh + 2 * TBUF;
        const ushort_t* sBl = sAh + 3 * TBUF;
        bf16x8 ah[4], al[4];
#pragma unroll
        for (int mt = 0; mt < 4; ++mt) {
            ah[mt] = *(const bf16x8*)&sAh[aoff[mt]];
            al[mt] = *(const bf16x8*)&sAl[aoff[mt]];
        }
#pragma unroll
        for (int nt = 0; nt < 4; ++nt) {
            bf16x8 bh = *(const bf16x8*)&sBh[boff[nt]];
            bf16x8 bl = *(const bf16x8*)&sBl[boff[nt]];
#pragma unroll
            for (int mt = 0; mt < 4; ++mt) {
                acc[mt][nt] = __builtin_amdgcn_mfma_f32_16x16x32_bf16(ah[mt], bh, acc[mt][nt], 0, 0, 0);
                acc[mt][nt] = __builtin_amdgcn_mfma_f32_16x16x32_bf16(al[mt], bh, acc[mt][nt], 0, 0, 0);
                acc[mt][nt] = __builtin_amdgcn_mfma_f32_16x16x32_bf16(ah[mt], bl, acc[mt][nt], 0, 0, 0);
            }
        }
        __builtin_amdgcn_sched_barrier(0);
        __builtin_amdgcn_s_barrier();                // all waves done reading buf[cur]
    }
}

// ---------------- GEMM 1: qkv = x @ Wqkv + bqkv -> scatter q,k,v [B,H,T,DK] ----------------
// 1D grid 1536, chunked XCD swizzle: XCD k owns contiguous m-tile range (A-panels ~4MB = one L2)
__global__ __launch_bounds__(256) void qkv_mfma(const ushort_t* __restrict__ xh,
                                                const ushort_t* __restrict__ xl,
                                                const ushort_t* __restrict__ wh,
                                                const ushort_t* __restrict__ wl,
                                                const float* __restrict__ bias,
                                                float* __restrict__ q,
                                                float* __restrict__ k,
                                                float* __restrict__ v)
{
    __shared__ ushort_t smem[2 * BUFU];              // 64 KiB
    f32x4 acc[4][4] = {};
    const int bid = blockIdx.x;
    const int swz = (bid & 7) * 192 + (bid >> 3);    // nwg=1536, cpx=192
    const int n0 = (swz % 24) * 128;
    const int m0 = (swz / 24) * 128;
    mfma_mainloop(xh, xl, wh, wl, m0, n0, smem, acc);

    const int tid = threadIdx.x, lane = tid & 63, w = tid >> 6;
    const int wm = (w >> 1) * 64, wn = (w & 1) * 64;
    const int c16 = lane & 15, rq = (lane >> 4) * 4;
#pragma unroll
    for (int mt = 0; mt < 4; ++mt)
#pragma unroll
        for (int nt = 0; nt < 4; ++nt)
#pragma unroll
            for (int r = 0; r < 4; ++r) {
                const int m = m0 + wm + mt * 16 + rq + r;
                const int n = n0 + wn + nt * 16 + c16;
                const float val = acc[mt][nt][r] + bias[n];
                const int bidx = m >> 9, t = m & (TT - 1);
                const int sel = n >> 10, d = n & (DD - 1);
                const int h = d >> 6, dk = d & (DKK - 1);
                float* dst = (sel == 0) ? q : (sel == 1) ? k : v;
                dst[((((size_t)bidx * HH + h) * TT + t) * DKK) + dk] = val;
            }
}

// ---------------- GEMM 2: out = ctx @ Wo + bo ----------------
__global__ __launch_bounds__(256) void out_mfma(const ushort_t* __restrict__ ah,
                                                const ushort_t* __restrict__ al,
                                                const ushort_t* __restrict__ wh,
                                                const ushort_t* __restrict__ wl,
                                                const float* __restrict__ bias,
                                                float* __restrict__ out)
{
    __shared__ ushort_t smem[2 * BUFU];              // 64 KiB
    f32x4 acc[4][4] = {};
    const int bid = blockIdx.x;
    const int swz = (bid & 7) * 64 + (bid >> 3);     // nwg=512, cpx=64
    const int n0 = (swz & 7) * 128;
    const int m0 = (swz >> 3) * 128;
    mfma_mainloop(ah, al, wh, wl, m0, n0, smem, acc);

    const int tid = threadIdx.x, lane = tid & 63, w = tid >> 6;
    const int wm = (w >> 1) * 64, wn = (w & 1) * 64;
    const int c16 = lane & 15, rq = (lane >> 4) * 4;
#pragma unroll
    for (int mt = 0; mt < 4; ++mt)
#pragma unroll
        for (int nt = 0; nt < 4; ++nt)
#pragma unroll
            for (int r = 0; r < 4; ++r) {
                const int m = m0 + wm + mt * 16 + rq + r;
                const int n = n0 + wn + nt * 16 + c16;
                out[(size_t)m * DD + n] = acc[mt][nt][r] + bias[n];
            }
}

// ---------------- Fused windowed attention, flash-style, 64-row tiles ----------------
// 1D grid with same-(b,h)->same-XCD swizzle (K/V L2 reuse across it-tiles);
// T14 register prefetch of next K/V chunk; nontemporal stores for the streamed attn matrix;
// fused bf16 hi/lo split of ctx in the epilogue.
__global__ __launch_bounds__(256) void attn_fused(const float* __restrict__ q,
                                                  const float* __restrict__ k,
                                                  const float* __restrict__ v,
                                                  const float* __restrict__ rel,
                                                  float* __restrict__ attn_out,
                                                  ushort_t* __restrict__ cxh,
                                                  ushort_t* __restrict__ cxl)
{
    // gid = u*64 + it*8 + bhlo;  xcd = gid%8 = bhlo -> all 8 it-tiles of one (b,h) share an XCD,
    // and each XCD runs few (b,h) streams at a time (256KB K/V fits its 4MB L2).
    const int gid = blockIdx.x;
    const int u = gid >> 6, rem = gid & 63;
    const int it = rem >> 3;
    const int bh_idx = u * 8 + (rem & 7);
    const int h = bh_idx & 15, b = bh_idx >> 4;
    const int i0 = it * TILE_M;
    int jbase = i0 - WIN; if (jbase < 0) jbase = 0; if (jbase > TT - JSPAN) jbase = TT - JSPAN;

    const int tid = threadIdx.x;
    const int tx = tid & 15, ty = tid >> 4;

    __shared__ float smem[2 * TILE_M * LSTR + 1024];
    float* buf0   = smem;
    float* buf1   = smem + TILE_M * LSTR;
    float* bias_s = smem + 2 * TILE_M * LSTR;

    const size_t bh = (size_t)b * HH + h;
    const float* qb = q + (bh * TT + i0) * DKK;
    const float* kb = k + bh * TT * DKK;
    const float* vb = v + bh * TT * DKK;
    float* arow = attn_out + (bh * TT + i0) * TT;

    // --- T14: issue K chunk-0 loads first; latency hides under zero-fill/bias/q staging ---
    const int kd = tid & 63, kr = tid >> 6;
    float kreg[16];
#pragma unroll
    for (int jj = 0; jj < 16; ++jj)
        kreg[jj] = kb[(size_t)(jbase + kr + jj * 4) * DKK + kd];

    {
        const f32x4 z = {0.f, 0.f, 0.f, 0.f};
        for (int idx = tid; idx < TILE_M * 48; idx += 256) {
            const int r  = idx / 48;
            const int c4 = idx - r * 48;
            const int col = (c4 * 4 < jbase) ? c4 * 4 : c4 * 4 + JSPAN;
            __builtin_nontemporal_store(z, (f32x4*)&arow[(size_t)r * TT + col]);
        }
    }

    for (int idx = tid; idx < 2 * MAXLEN - 1; idx += 256)
        bias_s[idx] = rel[(size_t)idx * HH + h];

    {
        const int d = tid & 63, r0 = tid >> 6;
#pragma unroll
        for (int ii = 0; ii < 16; ++ii) {
            const int i = r0 + ii * 4;
            buf0[d * LSTR + i] = qb[(size_t)i * DKK + d];
        }
    }

    float s[NCHUNK][4][4];
#pragma unroll 1
    for (int c = 0; c < NCHUNK; ++c) {
        __syncthreads();   // c=0: q/bias staged; c>0: prior chunk's buf1 reads done
#pragma unroll
        for (int jj = 0; jj < 16; ++jj)
            buf1[kd * LSTR + kr + jj * 4] = kreg[jj];
        if (c + 1 < NCHUNK) {
#pragma unroll
            for (int jj = 0; jj < 16; ++jj)
                kreg[jj] = kb[(size_t)(jbase + (c + 1) * 64 + kr + jj * 4) * DKK + kd];
        }
        __syncthreads();
        float acc[4][4] = {};
#pragma unroll
        for (int kk = 0; kk < 64; ++kk) {
            float4 a  = *(const float4*)&buf0[kk * LSTR + ty * 4];
            float4 b4 = *(const float4*)&buf1[kk * LSTR + tx * 4];
            float av[4] = {a.x, a.y, a.z, a.w};
            float bv[4] = {b4.x, b4.y, b4.z, b4.w};
#pragma unroll
            for (int r = 0; r < 4; ++r)
#pragma unroll
                for (int ccx = 0; ccx < 4; ++ccx)
                    acc[r][ccx] += av[r] * bv[ccx];
        }
#pragma unroll
        for (int r = 0; r < 4; ++r) {
            const int i = i0 + ty * 4 + r;
#pragma unroll
            for (int ccx = 0; ccx < 4; ++ccx) {
                const int j = jbase + c * 64 + tx * 4 + ccx;
                const int d = j - i;
                const float val = acc[r][ccx] * 0.125f + bias_s[d + MAXLEN - 1];
                s[c][r][ccx] = (d >= -WIN && d <= WIN) ? val : -INFINITY;
            }
        }
    }

    float mrow[4], sumr[4];
#pragma unroll
    for (int r = 0; r < 4; ++r) {
        float m = -INFINITY;
#pragma unroll
        for (int c = 0; c < NCHUNK; ++c)
#pragma unroll
            for (int ccx = 0; ccx < 4; ++ccx) m = fmaxf(m, s[c][r][ccx]);
        mrow[r] = m;
    }
#pragma unroll
    for (int off = 1; off < 16; off <<= 1)
#pragma unroll
        for (int r = 0; r < 4; ++r)
            mrow[r] = fmaxf(mrow[r], __shfl_xor(mrow[r], off));
#pragma unroll
    for (int r = 0; r < 4; ++r) sumr[r] = 0.f;
#pragma unroll
    for (int c = 0; c < NCHUNK; ++c)
#pragma unroll
        for (int r = 0; r < 4; ++r)
#pragma unroll
            for (int ccx = 0; ccx < 4; ++ccx) {
                const float e = __expf(s[c][r][ccx] - mrow[r]);
                s[c][r][ccx] = e;
                sumr[r] += e;
            }
#pragma unroll
    for (int off = 1; off < 16; off <<= 1)
#pragma unroll
        for (int r = 0; r < 4; ++r)
            sumr[r] += __shfl_xor(sumr[r], off);
    float invr[4];
#pragma unroll
    for (int r = 0; r < 4; ++r) invr[r] = 1.0f / sumr[r];
#pragma unroll
    for (int c = 0; c < NCHUNK; ++c)
#pragma unroll
        for (int r = 0; r < 4; ++r)
#pragma unroll
            for (int ccx = 0; ccx < 4; ++ccx)
                s[c][r][ccx] *= invr[r];

    // --- T14: V chunk-0 prefetch into regs ---
    const int vd4 = (tid & 15) * 4, vr = tid >> 4;
    float4 vreg[4];
#pragma unroll
    for (int jj = 0; jj < 4; ++jj)
        vreg[jj] = *(const float4*)&vb[(size_t)(jbase + vr + jj * 16) * DKK + vd4];

    float o[4][4] = {};
#pragma unroll 1
    for (int c = 0; c < NCHUNK; ++c) {
        __syncthreads();
#pragma unroll
        for (int r = 0; r < 4; ++r) {
            const f32x4 pv = {s[c][r][0], s[c][r][1], s[c][r][2], s[c][r][3]};
            __builtin_nontemporal_store(pv,
                (f32x4*)&arow[(size_t)(ty * 4 + r) * TT + jbase + c * 64 + tx * 4]);
#pragma unroll
            for (int ccx = 0; ccx < 4; ++ccx)
                buf0[(tx * 4 + ccx) * LSTR + ty * 4 + r] = s[c][r][ccx];
        }
#pragma unroll
        for (int jj = 0; jj < 4; ++jj)
            *(float4*)&buf1[(vr + jj * 16) * LSTR + vd4] = vreg[jj];
        if (c + 1 < NCHUNK) {
#pragma unroll
            for (int jj = 0; jj < 4; ++jj)
                vreg[jj] = *(const float4*)&vb[(size_t)(jbase + (c + 1) * 64 + vr + jj * 16) * DKK + vd4];
        }
        __syncthreads();
#pragma unroll
        for (int kk = 0; kk < 64; ++kk) {
            float4 a  = *(const float4*)&buf0[kk * LSTR + ty * 4];
            float4 b4 = *(const float4*)&buf1[kk * LSTR + tx * 4];
            float av[4] = {a.x, a.y, a.z, a.w};
            float bv[4] = {b4.x, b4.y, b4.z, b4.w};
#pragma unroll
            for (int r = 0; r < 4; ++r)
#pragma unroll
                for (int ccx = 0; ccx < 4; ++ccx)
                    o[r][ccx] += av[r] * bv[ccx];
        }
    }

    // --- fused ctx -> bf16 hi/lo split epilogue ([B,T,H,DK] layout, identical f2bf math) ---
#pragma unroll
    for (int r = 0; r < 4; ++r) {
        ushort_t hh[4], ll[4];
#pragma unroll
        for (int j = 0; j < 4; ++j) {
            const float val = o[r][j];
            hh[j] = f2bf(val);
            ll[j] = f2bf(val - bf2f(hh[j]));
        }
        const size_t off = (((size_t)b * TT + i0 + ty * 4 + r) * HH + h) * DKK + tx * 4;
        *(ushort4*)&cxh[off] = make_ushort4(hh[0], hh[1], hh[2], hh[3]);
        *(ushort4*)&cxl[off] = make_ushort4(ll[0], ll[1], ll[2], ll[3]);
    }
}

extern "C" void kernel_launch(void* const* d_in, const int* in_sizes, int n_in,
                              void* d_out, int out_size, void* d_ws, size_t ws_size,
                              hipStream_t stream)
{
    const float* x    = (const float*)d_in[0];
    const float* Wqkv = (const float*)d_in[1];
    const float* bqkv = (const float*)d_in[2];
    const float* Wo   = (const float*)d_in[3];
    const float* bo   = (const float*)d_in[4];
    const float* rel  = (const float*)d_in[5];

    float* out  = (float*)d_out;
    float* attn = out + (size_t)BB * TT * DD;

    const size_t per = (size_t)BB * HH * TT * DKK;   // 8,388,608
    float* q = (float*)d_ws;
    float* k = q + per;
    float* v = k + per;
    ushort_t* xh = (ushort_t*)(v + per);
    ushort_t* xl = xh + per;
    ushort_t* Wqh = (ushort_t*)(xl + per);
    ushort_t* Wql = Wqh + (size_t)DD * 3 * DD;
    ushort_t* cxh = xh;                      // aliases xh (dead after qkv_mfma)
    ushort_t* cxl = xl;                      // aliases xl (dead after qkv_mfma)
    ushort_t* Woh = (ushort_t*)v;            // aliases v (dead after attn)
    ushort_t* Wol = Woh + (size_t)DD * DD;

    const int n4x = BB * TT * DD / 4;        // 2,097,152

    conv_split<<<dim3((n4x + 255) / 256), 256, 0, stream>>>(x, xh, xl, n4x);
    conv_split_T<<<dim3(3 * DD / 32, DD / 32), 256, 0, stream>>>(Wqkv, Wqh, Wql, DD, 3 * DD);
    qkv_mfma<<<dim3(1536), 256, 0, stream>>>(xh, xl, Wqh, Wql, bqkv, q, k, v);
    attn_fused<<<dim3(2048), 256, 0, stream>>>(q, k, v, rel, attn, cxh, cxl);
    conv_split_T<<<dim3(DD / 32, DD / 32), 256, 0, stream>>>(Wo, Woh, Wol, DD, DD);
    out_mfma<<<dim3(512), 256, 0, stream>>>(cxh, cxl, Woh, Wol, bo, out);
}

// Round 5
// 651.363 us; speedup vs baseline: 1.2831x; 1.2205x over previous
//
#include <hip/hip_runtime.h>
#include <math.h>

typedef unsigned short ushort_t;
typedef __bf16 bf16x8 __attribute__((ext_vector_type(8)));
typedef float f32x4 __attribute__((ext_vector_type(4)));
typedef ushort_t u16x8 __attribute__((ext_vector_type(8)));

#define BB 16
#define TT 512
#define DD 1024
#define HH 16
#define DKK 64
#define WIN 128
#define MAXLEN 512

#define TILE_M 64
#define JSPAN 320
#define NCHUNK 5

#define BK 32                 // GEMM K-step in ushorts; LDS rows 64B, linear
#define TBUF (128 * BK)       // ushorts per tensor per buffer
#define BUFU (4 * TBUF)       // ushorts per buffer (4 tensors)
#define KSTEPS (DD / BK)      // 32

#define ALS 72                // attn LDS row stride in ushorts (144B = 9*16B: b128-aligned, rows 4 banks apart)

// async global->LDS, 16B per lane, wave-uniform LDS base + lane*16
#define GLOAD16(g, l)                                                                              \
    __builtin_amdgcn_global_load_lds((const __attribute__((address_space(1))) unsigned int*)(g),   \
                                     (__attribute__((address_space(3))) unsigned int*)(l), 16, 0, 0)

// ---------------- fp32 -> bf16 hi/lo split helpers ----------------
__device__ __forceinline__ ushort_t f2bf(float f) {
    union { float f; unsigned u; } x; x.f = f;
    unsigned r = x.u + 0x7fffu + ((x.u >> 16) & 1u);   // RTN-even
    return (ushort_t)(r >> 16);
}
__device__ __forceinline__ float bf2f(ushort_t h) {
    union { unsigned u; float f; } x; x.u = ((unsigned)h) << 16;
    return x.f;
}

// attn LDS index: row-stride 72 ushorts + XOR of (row>>3) onto the 16B slot.
// Applied identically on every write and read of the same tile (both-sides rule).
__device__ __forceinline__ int swi(int row, int col) {
    return row * ALS + (col ^ (((row >> 3) & 7) << 3));
}

// ---------------- conversion: A [M][K] fp32 -> hi/lo bf16 same layout ----------------
__global__ __launch_bounds__(256) void conv_split(const float* __restrict__ src,
                                                  ushort_t* __restrict__ hi,
                                                  ushort_t* __restrict__ lo, int n4)
{
    const int i = blockIdx.x * 256 + threadIdx.x;
    if (i >= n4) return;
    float4 vf = ((const float4*)src)[i];
    ushort_t h0 = f2bf(vf.x), h1 = f2bf(vf.y), h2 = f2bf(vf.z), h3 = f2bf(vf.w);
    ushort4 hv = make_ushort4(h0, h1, h2, h3);
    ushort4 lv = make_ushort4(f2bf(vf.x - bf2f(h0)), f2bf(vf.y - bf2f(h1)),
                              f2bf(vf.z - bf2f(h2)), f2bf(vf.w - bf2f(h3)));
    ((ushort4*)hi)[i] = hv;
    ((ushort4*)lo)[i] = lv;
}

// ---------------- conversion + transpose: W [K][N] fp32 -> [N][K] hi/lo bf16 ----------------
__global__ __launch_bounds__(256) void conv_split_T(const float* __restrict__ W,
                                                    ushort_t* __restrict__ hiT,
                                                    ushort_t* __restrict__ loT,
                                                    int K, int N)
{
    __shared__ ushort_t th[32][33], tl[32][33];
    const int n0 = blockIdx.x * 32, k0 = blockIdx.y * 32;
    const int tid = threadIdx.x;
    const int r = tid >> 3, c4 = (tid & 7) * 4;
    float4 vf = *(const float4*)&W[(size_t)(k0 + r) * N + n0 + c4];
    float vv[4] = {vf.x, vf.y, vf.z, vf.w};
#pragma unroll
    for (int j = 0; j < 4; ++j) {
        ushort_t h = f2bf(vv[j]);
        th[r][c4 + j] = h;
        tl[r][c4 + j] = f2bf(vv[j] - bf2f(h));
    }
    __syncthreads();
    ushort4 oh = make_ushort4(th[c4 + 0][r], th[c4 + 1][r], th[c4 + 2][r], th[c4 + 3][r]);
    ushort4 ol = make_ushort4(tl[c4 + 0][r], tl[c4 + 1][r], tl[c4 + 2][r], tl[c4 + 3][r]);
    *(ushort4*)&hiT[(size_t)(n0 + r) * K + k0 + c4] = oh;
    *(ushort4*)&loT[(size_t)(n0 + r) * K + k0 + c4] = ol;
}

// ---------------- split-bf16 MFMA mainloop, 2-phase double-buffered (unchanged) ----------------
__device__ __forceinline__ void mfma_mainloop(const ushort_t* __restrict__ Ah,
                                              const ushort_t* __restrict__ Al,
                                              const ushort_t* __restrict__ Bh,
                                              const ushort_t* __restrict__ Bl,
                                              int m0, int n0,
                                              ushort_t* smem, f32x4 (&acc)[4][4])
{
    const int tid = threadIdx.x;
    const int lane = tid & 63;
    const int w = tid >> 6;
    const int wm = (w >> 1) * 64, wn = (w & 1) * 64;
    const int c16 = lane & 15;
    const int quad = lane >> 4;

    const int lrow = lane >> 2, lq = lane & 3;
    const int r0 = w * 32, r1 = w * 32 + 16;
    const int row0 = r0 + lrow, row1 = r1 + lrow;
    const int qd0 = lq ^ ((row0 >> 1) & 3);
    const int qd1 = lq ^ ((row1 >> 1) & 3);
    const size_t a0 = (size_t)(m0 + row0) * DD + qd0 * 8;
    const size_t a1 = (size_t)(m0 + row1) * DD + qd1 * 8;
    const size_t b0 = (size_t)(n0 + row0) * DD + qd0 * 8;
    const size_t b1 = (size_t)(n0 + row1) * DD + qd1 * 8;

    auto STAGE = [&](int buf, int k0) {
        ushort_t* s_ = smem + buf * BUFU;
        GLOAD16(Ah + a0 + k0, (char*)s_ + r0 * 64);
        GLOAD16(Ah + a1 + k0, (char*)s_ + r1 * 64);
        GLOAD16(Al + a0 + k0, (char*)(s_ + TBUF) + r0 * 64);
        GLOAD16(Al + a1 + k0, (char*)(s_ + TBUF) + r1 * 64);
        GLOAD16(Bh + b0 + k0, (char*)(s_ + 2 * TBUF) + r0 * 64);
        GLOAD16(Bh + b1 + k0, (char*)(s_ + 2 * TBUF) + r1 * 64);
        GLOAD16(Bl + b0 + k0, (char*)(s_ + 3 * TBUF) + r0 * 64);
        GLOAD16(Bl + b1 + k0, (char*)(s_ + 3 * TBUF) + r1 * 64);
    };

    int aoff[4], boff[4];
#pragma unroll
    for (int mt = 0; mt < 4; ++mt) {
        const int row = wm + mt * 16 + c16;
        aoff[mt] = row * BK + ((quad ^ ((row >> 1) & 3)) * 8);
    }
#pragma unroll
    for (int nt = 0; nt < 4; ++nt) {
        const int row = wn + nt * 16 + c16;
        boff[nt] = row * BK + ((quad ^ ((row >> 1) & 3)) * 8);
    }

    STAGE(0, 0);
    for (int t = 0; t < KSTEPS; ++t) {
        const int cur = t & 1;
        if (t + 1 < KSTEPS) {
            STAGE(cur ^ 1, (t + 1) * BK);
            asm volatile("s_waitcnt vmcnt(8)" ::: "memory");
        } else {
            asm volatile("s_waitcnt vmcnt(0)" ::: "memory");
        }
        __builtin_amdgcn_sched_barrier(0);
        __builtin_amdgcn_s_barrier();

        const ushort_t* sAh = smem + cur * BUFU;
        const ushort_t* sAl = sAh + TBUF;
        const ushort_t* sBh = sAh + 2 * TBUF;
        const ushort_t* sBl = sAh + 3 * TBUF;
        bf16x8 ah[4], al[4];
#pragma unroll
        for (int mt = 0; mt < 4; ++mt) {
            ah[mt] = *(const bf16x8*)&sAh[aoff[mt]];
            al[mt] = *(const bf16x8*)&sAl[aoff[mt]];
        }
#pragma unroll
        for (int nt = 0; nt < 4; ++nt) {
            bf16x8 bh = *(const bf16x8*)&sBh[boff[nt]];
            bf16x8 bl = *(const bf16x8*)&sBl[boff[nt]];
#pragma unroll
            for (int mt = 0; mt < 4; ++mt) {
                acc[mt][nt] = __builtin_amdgcn_mfma_f32_16x16x32_bf16(ah[mt], bh, acc[mt][nt], 0, 0, 0);
                acc[mt][nt] = __builtin_amdgcn_mfma_f32_16x16x32_bf16(al[mt], bh, acc[mt][nt], 0, 0, 0);
                acc[mt][nt] = __builtin_amdgcn_mfma_f32_16x16x32_bf16(ah[mt], bl, acc[mt][nt], 0, 0, 0);
            }
        }
        __builtin_amdgcn_sched_barrier(0);
        __builtin_amdgcn_s_barrier();
    }
}

// ---------------- GEMM 1: qkv = x @ Wqkv + bqkv -> scatter bf16 hi/lo q,k,v [B,H,T,DK] ----------------
__global__ __launch_bounds__(256) void qkv_mfma(const ushort_t* __restrict__ xh,
                                                const ushort_t* __restrict__ xl,
                                                const ushort_t* __restrict__ wh,
                                                const ushort_t* __restrict__ wl,
                                                const float* __restrict__ bias,
                                                ushort_t* __restrict__ qh,
                                                ushort_t* __restrict__ ql,
                                                ushort_t* __restrict__ kh,
                                                ushort_t* __restrict__ kl,
                                                ushort_t* __restrict__ vh,
                                                ushort_t* __restrict__ vl)
{
    __shared__ ushort_t smem[2 * BUFU];              // 64 KiB
    f32x4 acc[4][4] = {};
    const int bid = blockIdx.x;
    const int swz = (bid & 7) * 192 + (bid >> 3);    // nwg=1536, cpx=192
    const int n0 = (swz % 24) * 128;
    const int m0 = (swz / 24) * 128;
    mfma_mainloop(xh, xl, wh, wl, m0, n0, smem, acc);

    const int tid = threadIdx.x, lane = tid & 63, w = tid >> 6;
    const int wm = (w >> 1) * 64, wn = (w & 1) * 64;
    const int c16 = lane & 15, rq = (lane >> 4) * 4;
#pragma unroll
    for (int mt = 0; mt < 4; ++mt)
#pragma unroll
        for (int nt = 0; nt < 4; ++nt)
#pragma unroll
            for (int r = 0; r < 4; ++r) {
                const int m = m0 + wm + mt * 16 + rq + r;
                const int n = n0 + wn + nt * 16 + c16;
                const float val = acc[mt][nt][r] + bias[n];
                const int bidx = m >> 9, t = m & (TT - 1);
                const int sel = n >> 10, d = n & (DD - 1);
                const int hd = d >> 6, dk = d & (DKK - 1);
                ushort_t* dsth = (sel == 0) ? qh : (sel == 1) ? kh : vh;
                ushort_t* dstl = (sel == 0) ? ql : (sel == 1) ? kl : vl;
                const size_t base = ((((size_t)bidx * HH + hd) * TT + t) * DKK) + dk;
                const ushort_t hi = f2bf(val);
                dsth[base] = hi;
                dstl[base] = f2bf(val - bf2f(hi));
            }
}

// ---------------- GEMM 2: out = ctx @ Wo + bo (unchanged) ----------------
__global__ __launch_bounds__(256) void out_mfma(const ushort_t* __restrict__ ah,
                                                const ushort_t* __restrict__ al,
                                                const ushort_t* __restrict__ wh,
                                                const ushort_t* __restrict__ wl,
                                                const float* __restrict__ bias,
                                                float* __restrict__ out)
{
    __shared__ ushort_t smem[2 * BUFU];              // 64 KiB
    f32x4 acc[4][4] = {};
    const int bid = blockIdx.x;
    const int swz = (bid & 7) * 64 + (bid >> 3);     // nwg=512, cpx=64
    const int n0 = (swz & 7) * 128;
    const int m0 = (swz >> 3) * 128;
    mfma_mainloop(ah, al, wh, wl, m0, n0, smem, acc);

    const int tid = threadIdx.x, lane = tid & 63, w = tid >> 6;
    const int wm = (w >> 1) * 64, wn = (w & 1) * 64;
    const int c16 = lane & 15, rq = (lane >> 4) * 4;
#pragma unroll
    for (int mt = 0; mt < 4; ++mt)
#pragma unroll
        for (int nt = 0; nt < 4; ++nt)
#pragma unroll
            for (int r = 0; r < 4; ++r) {
                const int m = m0 + wm + mt * 16 + rq + r;
                const int n = n0 + wn + nt * 16 + c16;
                out[(size_t)m * DD + n] = acc[mt][nt][r] + bias[n];
            }
}

// ---------------- Fused windowed attention, MFMA, 8 waves, fully static indexing ----------------
// S = Q K^T via 3-term split MFMA (same frag recipe as GEMM: A=[m][k]-contig rows, B=[n][k]-contig
// rows, C: col=lane&15, row=quad*4+reg). Full-span softmax with cross-wave LDS stats exchange.
// PV: P split to bf16 hi/lo in LDS (A-layout), V transposed into LDS on stage (B-layout).
// All score state in registers with compile-time indices (rule #20: no scratch).
__global__ __launch_bounds__(512) void attn_fused(const ushort_t* __restrict__ qh_g,
                                                  const ushort_t* __restrict__ ql_g,
                                                  const ushort_t* __restrict__ kh_g,
                                                  const ushort_t* __restrict__ kl_g,
                                                  const ushort_t* __restrict__ vh_g,
                                                  const ushort_t* __restrict__ vl_g,
                                                  const float* __restrict__ rel,
                                                  float* __restrict__ attn_out,
                                                  ushort_t* __restrict__ cxh,
                                                  ushort_t* __restrict__ cxl)
{
    // same-(b,h) -> same-XCD swizzle (kept from r3: FETCH -42%)
    const int gid = blockIdx.x;
    const int u = gid >> 6, rem = gid & 63;
    const int it = rem >> 3;
    const int bh_idx = u * 8 + (rem & 7);
    const int h = bh_idx & 15, b = bh_idx >> 4;
    const int i0 = it * TILE_M;
    int jbase = i0 - WIN; if (jbase < 0) jbase = 0; if (jbase > TT - JSPAN) jbase = TT - JSPAN;

    const int tid = threadIdx.x;
    const int lane = tid & 63, w = tid >> 6;
    const int c16 = lane & 15, quad = lane >> 4, rq = quad * 4;
    const int wmh = (w >> 2) * 32;       // m-half (rows of Q / O owned by this wave)
    const int wnq = (w & 3) * 16;        // n-quarter (j-cols within chunk for S; dk-cols for O)

    __shared__ ushort_t sA0[64 * ALS], sA1[64 * ALS];   // Qh/Ql, then Ph/Pl
    __shared__ ushort_t sB0[64 * ALS], sB1[64 * ALS];   // Kh/Kl chunk, then V^T h/l chunk
    __shared__ float bias_s[1024];
    __shared__ float stats0[256], stats1[256];          // [i][wq]

    const size_t bh = (size_t)b * HH + h;
    const ushort_t* qhp = qh_g + (bh * TT + i0) * DKK;
    const ushort_t* qlp = ql_g + (bh * TT + i0) * DKK;
    const ushort_t* khp = kh_g + bh * TT * DKK;
    const ushort_t* klp = kl_g + bh * TT * DKK;
    const ushort_t* vhp = vh_g + bh * TT * DKK;
    const ushort_t* vlp = vl_g + bh * TT * DKK;
    float* arow = attn_out + (bh * TT + i0) * TT;

    // zero-fill outside-JSPAN region of attn matrix
    {
        const float4 z = make_float4(0.f, 0.f, 0.f, 0.f);
        for (int idx = tid; idx < TILE_M * 48; idx += 512) {
            const int r  = idx / 48;
            const int c4 = idx - r * 48;
            const int col = (c4 * 4 < jbase) ? c4 * 4 : c4 * 4 + JSPAN;
            *(float4*)&arow[(size_t)r * TT + col] = z;
        }
    }
    for (int idx = tid; idx < 2 * MAXLEN - 1; idx += 512)
        bias_s[idx] = rel[(size_t)idx * HH + h];

    // stage Q (64 rows x 64 dk, hi/lo)
    const int srow = tid >> 3, spart = (tid & 7) * 8;
    *(u16x8*)&sA0[swi(srow, spart)] = *(const u16x8*)&qhp[(size_t)srow * DKK + spart];
    *(u16x8*)&sA1[swi(srow, spart)] = *(const u16x8*)&qlp[(size_t)srow * DKK + spart];

    float s[NCHUNK][2][4];
#pragma unroll
    for (int c = 0; c < NCHUNK; ++c) {
        // stage K chunk
        {
            const size_t g = (size_t)(jbase + c * 64 + srow) * DKK + spart;
            *(u16x8*)&sB0[swi(srow, spart)] = *(const u16x8*)&khp[g];
            *(u16x8*)&sB1[swi(srow, spart)] = *(const u16x8*)&klp[g];
        }
        __syncthreads();
        f32x4 sacc[2] = {};
#pragma unroll
        for (int kk = 0; kk < 2; ++kk) {
            const int ku = kk * 32 + quad * 8;
            const bf16x8 kbh = *(const bf16x8*)&sB0[swi(wnq + c16, ku)];
            const bf16x8 kbl = *(const bf16x8*)&sB1[swi(wnq + c16, ku)];
#pragma unroll
            for (int mt = 0; mt < 2; ++mt) {
                const bf16x8 qah = *(const bf16x8*)&sA0[swi(wmh + mt * 16 + c16, ku)];
                const bf16x8 qal = *(const bf16x8*)&sA1[swi(wmh + mt * 16 + c16, ku)];
                sacc[mt] = __builtin_amdgcn_mfma_f32_16x16x32_bf16(qah, kbh, sacc[mt], 0, 0, 0);
                sacc[mt] = __builtin_amdgcn_mfma_f32_16x16x32_bf16(qal, kbh, sacc[mt], 0, 0, 0);
                sacc[mt] = __builtin_amdgcn_mfma_f32_16x16x32_bf16(qah, kbl, sacc[mt], 0, 0, 0);
            }
        }
        __syncthreads();
#pragma unroll
        for (int mt = 0; mt < 2; ++mt)
#pragma unroll
            for (int r = 0; r < 4; ++r) {
                const int i = i0 + wmh + mt * 16 + rq + r;
                const int j = jbase + c * 64 + wnq + c16;
                const int d = j - i;
                const float val = sacc[mt][r] * 0.125f + bias_s[d + MAXLEN - 1];
                s[c][mt][r] = (d >= -WIN && d <= WIN) ? val : -INFINITY;
            }
    }

    // ---- full-span softmax: in-lane (5) -> 16-lane shuffle -> cross-wave via stats ----
    float mrow[2][4];
#pragma unroll
    for (int mt = 0; mt < 2; ++mt)
#pragma unroll
        for (int r = 0; r < 4; ++r) {
            float m = s[0][mt][r];
#pragma unroll
            for (int c = 1; c < NCHUNK; ++c) m = fmaxf(m, s[c][mt][r]);
            mrow[mt][r] = m;
        }
#pragma unroll
    for (int off = 1; off < 16; off <<= 1)
#pragma unroll
        for (int mt = 0; mt < 2; ++mt)
#pragma unroll
            for (int r = 0; r < 4; ++r)
                mrow[mt][r] = fmaxf(mrow[mt][r], __shfl_xor(mrow[mt][r], off));
    if (c16 == 0) {
#pragma unroll
        for (int mt = 0; mt < 2; ++mt)
#pragma unroll
            for (int r = 0; r < 4; ++r)
                stats0[(wmh + mt * 16 + rq + r) * 4 + (w & 3)] = mrow[mt][r];
    }
    __syncthreads();
#pragma unroll
    for (int mt = 0; mt < 2; ++mt)
#pragma unroll
        for (int r = 0; r < 4; ++r) {
            const f32x4 q4 = *(const f32x4*)&stats0[(wmh + mt * 16 + rq + r) * 4];
            mrow[mt][r] = fmaxf(fmaxf(q4[0], q4[1]), fmaxf(q4[2], q4[3]));
        }
    float srow_[2][4];
#pragma unroll
    for (int mt = 0; mt < 2; ++mt)
#pragma unroll
        for (int r = 0; r < 4; ++r) srow_[mt][r] = 0.f;
#pragma unroll
    for (int c = 0; c < NCHUNK; ++c)
#pragma unroll
        for (int mt = 0; mt < 2; ++mt)
#pragma unroll
            for (int r = 0; r < 4; ++r) {
                const float e = __expf(s[c][mt][r] - mrow[mt][r]);
                s[c][mt][r] = e;
                srow_[mt][r] += e;
            }
#pragma unroll
    for (int off = 1; off < 16; off <<= 1)
#pragma unroll
        for (int mt = 0; mt < 2; ++mt)
#pragma unroll
            for (int r = 0; r < 4; ++r)
                srow_[mt][r] += __shfl_xor(srow_[mt][r], off);
    if (c16 == 0) {
#pragma unroll
        for (int mt = 0; mt < 2; ++mt)
#pragma unroll
            for (int r = 0; r < 4; ++r)
                stats1[(wmh + mt * 16 + rq + r) * 4 + (w & 3)] = srow_[mt][r];
    }
    __syncthreads();
    float inv[2][4];
#pragma unroll
    for (int mt = 0; mt < 2; ++mt)
#pragma unroll
        for (int r = 0; r < 4; ++r) {
            const f32x4 q4 = *(const f32x4*)&stats1[(wmh + mt * 16 + rq + r) * 4];
            inv[mt][r] = 1.0f / (q4[0] + q4[1] + q4[2] + q4[3]);
        }

    // ---- PV phase: per chunk, P -> global + LDS(bf16 split), V^T -> LDS, MFMA ----
    f32x4 oacc[2] = {};
#pragma unroll
    for (int c = 0; c < NCHUNK; ++c) {
        if (c > 0) __syncthreads();   // prior chunk's frag reads done before overwrite
#pragma unroll
        for (int mt = 0; mt < 2; ++mt)
#pragma unroll
            for (int r = 0; r < 4; ++r) {
                const int i = wmh + mt * 16 + rq + r;
                const float p = s[c][mt][r] * inv[mt][r];
                arow[(size_t)i * TT + jbase + c * 64 + wnq + c16] = p;
                const ushort_t ph = f2bf(p);
                const int col = (wnq + c16) ^ (((i >> 3) & 7) << 3);
                sA0[i * ALS + col] = ph;
                sA1[i * ALS + col] = f2bf(p - bf2f(ph));
            }
        // stage V^T: read rows [j][dk] coalesced, scatter to [dk][j]
        {
            const int jr = tid >> 3, dkb = (tid & 7) * 8;
            const size_t g = (size_t)(jbase + c * 64 + jr) * DKK + dkb;
            const u16x8 v0 = *(const u16x8*)&vhp[g];
            const u16x8 v1 = *(const u16x8*)&vlp[g];
#pragma unroll
            for (int e = 0; e < 8; ++e) {
                const int dk = dkb + e;
                const int idx = dk * ALS + (jr ^ (((dk >> 3) & 7) << 3));
                sB0[idx] = v0[e];
                sB1[idx] = v1[e];
            }
        }
        __syncthreads();
#pragma unroll
        for (int kk = 0; kk < 2; ++kk) {
            const int ku = kk * 32 + quad * 8;
            const bf16x8 vbh = *(const bf16x8*)&sB0[swi(wnq + c16, ku)];
            const bf16x8 vbl = *(const bf16x8*)&sB1[swi(wnq + c16, ku)];
#pragma unroll
            for (int mt = 0; mt < 2; ++mt) {
                const bf16x8 pah = *(const bf16x8*)&sA0[swi(wmh + mt * 16 + c16, ku)];
                const bf16x8 pal = *(const bf16x8*)&sA1[swi(wmh + mt * 16 + c16, ku)];
                oacc[mt] = __builtin_amdgcn_mfma_f32_16x16x32_bf16(pah, vbh, oacc[mt], 0, 0, 0);
                oacc[mt] = __builtin_amdgcn_mfma_f32_16x16x32_bf16(pal, vbh, oacc[mt], 0, 0, 0);
                oacc[mt] = __builtin_amdgcn_mfma_f32_16x16x32_bf16(pah, vbl, oacc[mt], 0, 0, 0);
            }
        }
    }

    // ---- fused ctx -> bf16 hi/lo split epilogue ([B,T,H,DK] layout) ----
#pragma unroll
    for (int mt = 0; mt < 2; ++mt)
#pragma unroll
        for (int r = 0; r < 4; ++r) {
            const float val = oacc[mt][r];
            const int i = wmh + mt * 16 + rq + r;
            const int dk = wnq + c16;
            const ushort_t hh2 = f2bf(val);
            const size_t off = (((size_t)b * TT + i0 + i) * HH + h) * DKK + dk;
            cxh[off] = hh2;
            cxl[off] = f2bf(val - bf2f(hh2));
        }
}

extern "C" void kernel_launch(void* const* d_in, const int* in_sizes, int n_in,
                              void* d_out, int out_size, void* d_ws, size_t ws_size,
                              hipStream_t stream)
{
    const float* x    = (const float*)d_in[0];
    const float* Wqkv = (const float*)d_in[1];
    const float* bqkv = (const float*)d_in[2];
    const float* Wo   = (const float*)d_in[3];
    const float* bo   = (const float*)d_in[4];
    const float* rel  = (const float*)d_in[5];

    float* out  = (float*)d_out;
    float* attn = out + (size_t)BB * TT * DD;

    const size_t per = (size_t)BB * HH * TT * DKK;   // 8,388,608 elements
    ushort_t* qh = (ushort_t*)d_ws;
    ushort_t* ql = qh + per;
    ushort_t* kh = ql + per;
    ushort_t* kl = kh + per;
    ushort_t* vh = kl + per;
    ushort_t* vl = vh + per;
    ushort_t* xh = vl + per;
    ushort_t* xl = xh + per;
    ushort_t* Wqh = xl + per;
    ushort_t* Wql = Wqh + (size_t)DD * 3 * DD;
    ushort_t* cxh = xh;                      // aliases xh (dead after qkv_mfma)
    ushort_t* cxl = xl;                      // aliases xl (dead after qkv_mfma)
    ushort_t* Woh = vh;                      // aliases vh (dead after attn)
    ushort_t* Wol = Woh + (size_t)DD * DD;

    const int n4x = BB * TT * DD / 4;        // 2,097,152

    conv_split<<<dim3((n4x + 255) / 256), 256, 0, stream>>>(x, xh, xl, n4x);
    conv_split_T<<<dim3(3 * DD / 32, DD / 32), 256, 0, stream>>>(Wqkv, Wqh, Wql, DD, 3 * DD);
    qkv_mfma<<<dim3(1536), 256, 0, stream>>>(xh, xl, Wqh, Wql, bqkv, qh, ql, kh, kl, vh, vl);
    attn_fused<<<dim3(2048), 512, 0, stream>>>(qh, ql, kh, kl, vh, vl, rel, attn, cxh, cxl);
    conv_split_T<<<dim3(DD / 32, DD / 32), 256, 0, stream>>>(Wo, Woh, Wol, DD, DD);
    out_mfma<<<dim3(512), 256, 0, stream>>>(cxh, cxl, Woh, Wol, bo, out);
}

// Round 6
// 625.713 us; speedup vs baseline: 1.3357x; 1.0410x over previous
//
#include <hip/hip_runtime.h>
#include <math.h>

typedef unsigned short ushort_t;
typedef __bf16 bf16x8 __attribute__((ext_vector_type(8)));
typedef float f32x4 __attribute__((ext_vector_type(4)));
typedef ushort_t u16x8 __attribute__((ext_vector_type(8)));

#define BB 16
#define TT 512
#define DD 1024
#define HH 16
#define DKK 64
#define WIN 128
#define MAXLEN 512

#define TILE_M 64
#define JSPAN 320
#define NCHUNK 5

#define BK 32                 // GEMM K-step in ushorts; LDS rows 64B, linear
#define TBUF (128 * BK)       // ushorts per tensor per buffer
#define BUFU (4 * TBUF)       // ushorts per buffer (4 tensors)
#define KSTEPS (DD / BK)      // 32

#define ALS 72                // attn LDS row stride in ushorts (144B: b128-aligned, rows 4 banks apart)

// async global->LDS, 16B per lane, wave-uniform LDS base + lane*16
#define GLOAD16(g, l)                                                                              \
    __builtin_amdgcn_global_load_lds((const __attribute__((address_space(1))) unsigned int*)(g),   \
                                     (__attribute__((address_space(3))) unsigned int*)(l), 16, 0, 0)

// ---------------- fp32 -> bf16 hi/lo split helpers ----------------
__device__ __forceinline__ ushort_t f2bf(float f) {
    union { float f; unsigned u; } x; x.f = f;
    unsigned r = x.u + 0x7fffu + ((x.u >> 16) & 1u);   // RTN-even
    return (ushort_t)(r >> 16);
}
__device__ __forceinline__ float bf2f(ushort_t h) {
    union { unsigned u; float f; } x; x.u = ((unsigned)h) << 16;
    return x.f;
}

// attn LDS index: row-stride 72 ushorts + XOR of (row>>3) onto the 16B slot.
// Applied identically on every write and read of the same tile (both-sides rule).
__device__ __forceinline__ int swi(int row, int col) {
    return row * ALS + (col ^ (((row >> 3) & 7) << 3));
}

// ---------------- conversion: A [M][K] fp32 -> hi/lo bf16 same layout ----------------
__global__ __launch_bounds__(256) void conv_split(const float* __restrict__ src,
                                                  ushort_t* __restrict__ hi,
                                                  ushort_t* __restrict__ lo, int n4)
{
    const int i = blockIdx.x * 256 + threadIdx.x;
    if (i >= n4) return;
    float4 vf = ((const float4*)src)[i];
    ushort_t h0 = f2bf(vf.x), h1 = f2bf(vf.y), h2 = f2bf(vf.z), h3 = f2bf(vf.w);
    ushort4 hv = make_ushort4(h0, h1, h2, h3);
    ushort4 lv = make_ushort4(f2bf(vf.x - bf2f(h0)), f2bf(vf.y - bf2f(h1)),
                              f2bf(vf.z - bf2f(h2)), f2bf(vf.w - bf2f(h3)));
    ((ushort4*)hi)[i] = hv;
    ((ushort4*)lo)[i] = lv;
}

// ---------------- conversion + transpose: W [K][N] fp32 -> [N][K] hi/lo bf16 ----------------
__global__ __launch_bounds__(256) void conv_split_T(const float* __restrict__ W,
                                                    ushort_t* __restrict__ hiT,
                                                    ushort_t* __restrict__ loT,
                                                    int K, int N)
{
    __shared__ ushort_t th[32][33], tl[32][33];
    const int n0 = blockIdx.x * 32, k0 = blockIdx.y * 32;
    const int tid = threadIdx.x;
    const int r = tid >> 3, c4 = (tid & 7) * 4;
    float4 vf = *(const float4*)&W[(size_t)(k0 + r) * N + n0 + c4];
    float vv[4] = {vf.x, vf.y, vf.z, vf.w};
#pragma unroll
    for (int j = 0; j < 4; ++j) {
        ushort_t h = f2bf(vv[j]);
        th[r][c4 + j] = h;
        tl[r][c4 + j] = f2bf(vv[j] - bf2f(h));
    }
    __syncthreads();
    ushort4 oh = make_ushort4(th[c4 + 0][r], th[c4 + 1][r], th[c4 + 2][r], th[c4 + 3][r]);
    ushort4 ol = make_ushort4(tl[c4 + 0][r], tl[c4 + 1][r], tl[c4 + 2][r], tl[c4 + 3][r]);
    *(ushort4*)&hiT[(size_t)(n0 + r) * K + k0 + c4] = oh;
    *(ushort4*)&loT[(size_t)(n0 + r) * K + k0 + c4] = ol;
}

// ---------------- split-bf16 MFMA mainloop, 2-phase double-buffered (unchanged) ----------------
__device__ __forceinline__ void mfma_mainloop(const ushort_t* __restrict__ Ah,
                                              const ushort_t* __restrict__ Al,
                                              const ushort_t* __restrict__ Bh,
                                              const ushort_t* __restrict__ Bl,
                                              int m0, int n0,
                                              ushort_t* smem, f32x4 (&acc)[4][4])
{
    const int tid = threadIdx.x;
    const int lane = tid & 63;
    const int w = tid >> 6;
    const int wm = (w >> 1) * 64, wn = (w & 1) * 64;
    const int c16 = lane & 15;
    const int quad = lane >> 4;

    const int lrow = lane >> 2, lq = lane & 3;
    const int r0 = w * 32, r1 = w * 32 + 16;
    const int row0 = r0 + lrow, row1 = r1 + lrow;
    const int qd0 = lq ^ ((row0 >> 1) & 3);
    const int qd1 = lq ^ ((row1 >> 1) & 3);
    const size_t a0 = (size_t)(m0 + row0) * DD + qd0 * 8;
    const size_t a1 = (size_t)(m0 + row1) * DD + qd1 * 8;
    const size_t b0 = (size_t)(n0 + row0) * DD + qd0 * 8;
    const size_t b1 = (size_t)(n0 + row1) * DD + qd1 * 8;

    auto STAGE = [&](int buf, int k0) {
        ushort_t* s_ = smem + buf * BUFU;
        GLOAD16(Ah + a0 + k0, (char*)s_ + r0 * 64);
        GLOAD16(Ah + a1 + k0, (char*)s_ + r1 * 64);
        GLOAD16(Al + a0 + k0, (char*)(s_ + TBUF) + r0 * 64);
        GLOAD16(Al + a1 + k0, (char*)(s_ + TBUF) + r1 * 64);
        GLOAD16(Bh + b0 + k0, (char*)(s_ + 2 * TBUF) + r0 * 64);
        GLOAD16(Bh + b1 + k0, (char*)(s_ + 2 * TBUF) + r1 * 64);
        GLOAD16(Bl + b0 + k0, (char*)(s_ + 3 * TBUF) + r0 * 64);
        GLOAD16(Bl + b1 + k0, (char*)(s_ + 3 * TBUF) + r1 * 64);
    };

    int aoff[4], boff[4];
#pragma unroll
    for (int mt = 0; mt < 4; ++mt) {
        const int row = wm + mt * 16 + c16;
        aoff[mt] = row * BK + ((quad ^ ((row >> 1) & 3)) * 8);
    }
#pragma unroll
    for (int nt = 0; nt < 4; ++nt) {
        const int row = wn + nt * 16 + c16;
        boff[nt] = row * BK + ((quad ^ ((row >> 1) & 3)) * 8);
    }

    STAGE(0, 0);
    for (int t = 0; t < KSTEPS; ++t) {
        const int cur = t & 1;
        if (t + 1 < KSTEPS) {
            STAGE(cur ^ 1, (t + 1) * BK);
            asm volatile("s_waitcnt vmcnt(8)" ::: "memory");
        } else {
            asm volatile("s_waitcnt vmcnt(0)" ::: "memory");
        }
        __builtin_amdgcn_sched_barrier(0);
        __builtin_amdgcn_s_barrier();

        const ushort_t* sAh = smem + cur * BUFU;
        const ushort_t* sAl = sAh + TBUF;
        const ushort_t* sBh = sAh + 2 * TBUF;
        const ushort_t* sBl = sAh + 3 * TBUF;
        bf16x8 ah[4], al[4];
#pragma unroll
        for (int mt = 0; mt < 4; ++mt) {
            ah[mt] = *(const bf16x8*)&sAh[aoff[mt]];
            al[mt] = *(const bf16x8*)&sAl[aoff[mt]];
        }
#pragma unroll
        for (int nt = 0; nt < 4; ++nt) {
            bf16x8 bh = *(const bf16x8*)&sBh[boff[nt]];
            bf16x8 bl = *(const bf16x8*)&sBl[boff[nt]];
#pragma unroll
            for (int mt = 0; mt < 4; ++mt) {
                acc[mt][nt] = __builtin_amdgcn_mfma_f32_16x16x32_bf16(ah[mt], bh, acc[mt][nt], 0, 0, 0);
                acc[mt][nt] = __builtin_amdgcn_mfma_f32_16x16x32_bf16(al[mt], bh, acc[mt][nt], 0, 0, 0);
                acc[mt][nt] = __builtin_amdgcn_mfma_f32_16x16x32_bf16(ah[mt], bl, acc[mt][nt], 0, 0, 0);
            }
        }
        __builtin_amdgcn_sched_barrier(0);
        __builtin_amdgcn_s_barrier();
    }
}

// ---------------- GEMM 1 (unchanged) ----------------
__global__ __launch_bounds__(256) void qkv_mfma(const ushort_t* __restrict__ xh,
                                                const ushort_t* __restrict__ xl,
                                                const ushort_t* __restrict__ wh,
                                                const ushort_t* __restrict__ wl,
                                                const float* __restrict__ bias,
                                                ushort_t* __restrict__ qh,
                                                ushort_t* __restrict__ ql,
                                                ushort_t* __restrict__ kh,
                                                ushort_t* __restrict__ kl,
                                                ushort_t* __restrict__ vh,
                                                ushort_t* __restrict__ vl)
{
    __shared__ ushort_t smem[2 * BUFU];              // 64 KiB
    f32x4 acc[4][4] = {};
    const int bid = blockIdx.x;
    const int swz = (bid & 7) * 192 + (bid >> 3);    // nwg=1536, cpx=192
    const int n0 = (swz % 24) * 128;
    const int m0 = (swz / 24) * 128;
    mfma_mainloop(xh, xl, wh, wl, m0, n0, smem, acc);

    const int tid = threadIdx.x, lane = tid & 63, w = tid >> 6;
    const int wm = (w >> 1) * 64, wn = (w & 1) * 64;
    const int c16 = lane & 15, rq = (lane >> 4) * 4;
#pragma unroll
    for (int mt = 0; mt < 4; ++mt)
#pragma unroll
        for (int nt = 0; nt < 4; ++nt)
#pragma unroll
            for (int r = 0; r < 4; ++r) {
                const int m = m0 + wm + mt * 16 + rq + r;
                const int n = n0 + wn + nt * 16 + c16;
                const float val = acc[mt][nt][r] + bias[n];
                const int bidx = m >> 9, t = m & (TT - 1);
                const int sel = n >> 10, d = n & (DD - 1);
                const int hd = d >> 6, dk = d & (DKK - 1);
                ushort_t* dsth = (sel == 0) ? qh : (sel == 1) ? kh : vh;
                ushort_t* dstl = (sel == 0) ? ql : (sel == 1) ? kl : vl;
                const size_t base = ((((size_t)bidx * HH + hd) * TT + t) * DKK) + dk;
                const ushort_t hi = f2bf(val);
                dsth[base] = hi;
                dstl[base] = f2bf(val - bf2f(hi));
            }
}

// ---------------- GEMM 2 (unchanged) ----------------
__global__ __launch_bounds__(256) void out_mfma(const ushort_t* __restrict__ ah,
                                                const ushort_t* __restrict__ al,
                                                const ushort_t* __restrict__ wh,
                                                const ushort_t* __restrict__ wl,
                                                const float* __restrict__ bias,
                                                float* __restrict__ out)
{
    __shared__ ushort_t smem[2 * BUFU];              // 64 KiB
    f32x4 acc[4][4] = {};
    const int bid = blockIdx.x;
    const int swz = (bid & 7) * 64 + (bid >> 3);     // nwg=512, cpx=64
    const int n0 = (swz & 7) * 128;
    const int m0 = (swz >> 3) * 128;
    mfma_mainloop(ah, al, wh, wl, m0, n0, smem, acc);

    const int tid = threadIdx.x, lane = tid & 63, w = tid >> 6;
    const int wm = (w >> 1) * 64, wn = (w & 1) * 64;
    const int c16 = lane & 15, rq = (lane >> 4) * 4;
#pragma unroll
    for (int mt = 0; mt < 4; ++mt)
#pragma unroll
        for (int nt = 0; nt < 4; ++nt)
#pragma unroll
            for (int r = 0; r < 4; ++r) {
                const int m = m0 + wm + mt * 16 + rq + r;
                const int n = n0 + wn + nt * 16 + c16;
                out[(size_t)m * DD + n] = acc[mt][nt][r] + bias[n];
            }
}

// ---------------- Fused windowed attention: 4-wave blocks, 32 q-rows, T14 prefetch ----------------
__global__ __launch_bounds__(256) void attn_fused(const ushort_t* __restrict__ qh_g,
                                                  const ushort_t* __restrict__ ql_g,
                                                  const ushort_t* __restrict__ kh_g,
                                                  const ushort_t* __restrict__ kl_g,
                                                  const ushort_t* __restrict__ vh_g,
                                                  const ushort_t* __restrict__ vl_g,
                                                  const float* __restrict__ rel,
                                                  float* __restrict__ attn_out,
                                                  ushort_t* __restrict__ cxh,
                                                  ushort_t* __restrict__ cxl)
{
    const int gid = blockIdx.x;
    const int x = gid & 7;
    const int v = (gid >> 3) & 15;
    const int u = gid >> 7;
    const int it = v >> 1, mh = v & 1;
    const int bh_idx = u * 8 + x;
    const int h = bh_idx & 15, b = bh_idx >> 4;
    const int i0 = it * TILE_M;
    int jbase = i0 - WIN; if (jbase < 0) jbase = 0; if (jbase > TT - JSPAN) jbase = TT - JSPAN;
    const int irow0 = i0 + mh * 32;

    const int tid = threadIdx.x;
    const int lane = tid & 63, w = tid >> 6;
    const int c16 = lane & 15, quad = lane >> 4, rq = quad * 4;
    const int wnq = w * 16;

    __shared__ ushort_t sA0[32 * ALS], sA1[32 * ALS];
    __shared__ ushort_t sB0[64 * ALS], sB1[64 * ALS];
    __shared__ float bias_s[260];
    __shared__ float stats0[128], stats1[128];

    const size_t bh = (size_t)b * HH + h;
    const ushort_t* qhp = qh_g + (bh * TT + irow0) * DKK;
    const ushort_t* qlp = ql_g + (bh * TT + irow0) * DKK;
    const ushort_t* khp = kh_g + bh * TT * DKK;
    const ushort_t* klp = kl_g + bh * TT * DKK;
    const ushort_t* vhp = vh_g + bh * TT * DKK;
    const ushort_t* vlp = vl_g + bh * TT * DKK;
    float* arow = attn_out + (bh * TT + irow0) * TT;

    const int srow = tid >> 3, spart = (tid & 7) * 8;

    // T14: K chunk-0 prefetch first
    u16x8 kpre[2][2];
#pragma unroll
    for (int ii = 0; ii < 2; ++ii) {
        const size_t g = (size_t)(jbase + ii * 32 + srow) * DKK + spart;
        kpre[ii][0] = *(const u16x8*)&khp[g];
        kpre[ii][1] = *(const u16x8*)&klp[g];
    }

    {
        const float4 z = make_float4(0.f, 0.f, 0.f, 0.f);
        for (int idx = tid; idx < 32 * 48; idx += 256) {
            const int r  = idx / 48;
            const int c4 = idx - r * 48;
            const int col = (c4 * 4 < jbase) ? c4 * 4 : c4 * 4 + JSPAN;
            *(float4*)&arow[(size_t)r * TT + col] = z;
        }
    }
    if (tid < 257) bias_s[tid] = rel[(size_t)(tid + MAXLEN - 1 - 128) * HH + h];

    *(u16x8*)&sA0[swi(srow, spart)] = *(const u16x8*)&qhp[(size_t)srow * DKK + spart];
    *(u16x8*)&sA1[swi(srow, spart)] = *(const u16x8*)&qlp[(size_t)srow * DKK + spart];

    float s[NCHUNK][8];                 // [chunk][mt*4+r], all static indices
#pragma unroll
    for (int c = 0; c < NCHUNK; ++c) {
#pragma unroll
        for (int ii = 0; ii < 2; ++ii) {
            *(u16x8*)&sB0[swi(ii * 32 + srow, spart)] = kpre[ii][0];
            *(u16x8*)&sB1[swi(ii * 32 + srow, spart)] = kpre[ii][1];
        }
        if (c + 1 < NCHUNK) {
#pragma unroll
            for (int ii = 0; ii < 2; ++ii) {
                const size_t g = (size_t)(jbase + (c + 1) * 64 + ii * 32 + srow) * DKK + spart;
                kpre[ii][0] = *(const u16x8*)&khp[g];
                kpre[ii][1] = *(const u16x8*)&klp[g];
            }
        }
        __syncthreads();
        f32x4 sacc[2] = {};
#pragma unroll
        for (int kk = 0; kk < 2; ++kk) {
            const int ku = kk * 32 + quad * 8;
            const bf16x8 kbh = *(const bf16x8*)&sB0[swi(wnq + c16, ku)];
            const bf16x8 kbl = *(const bf16x8*)&sB1[swi(wnq + c16, ku)];
#pragma unroll
            for (int mt = 0; mt < 2; ++mt) {
                const bf16x8 qah = *(const bf16x8*)&sA0[swi(mt * 16 + c16, ku)];
                const bf16x8 qal = *(const bf16x8*)&sA1[swi(mt * 16 + c16, ku)];
                sacc[mt] = __builtin_amdgcn_mfma_f32_16x16x32_bf16(qah, kbh, sacc[mt], 0, 0, 0);
                sacc[mt] = __builtin_amdgcn_mfma_f32_16x16x32_bf16(qal, kbh, sacc[mt], 0, 0, 0);
                sacc[mt] = __builtin_amdgcn_mfma_f32_16x16x32_bf16(qah, kbl, sacc[mt], 0, 0, 0);
            }
        }
        __syncthreads();
#pragma unroll
        for (int mt = 0; mt < 2; ++mt)
#pragma unroll
            for (int r = 0; r < 4; ++r) {
                const int i = irow0 + mt * 16 + rq + r;
                const int j = jbase + c * 64 + wnq + c16;
                const int d = j - i;
                const int bi = (d < -128) ? -128 : (d > 128 ? 128 : d);
                const float val = sacc[mt][r] * 0.125f + bias_s[bi + 128];
                s[c][mt * 4 + r] = (d >= -WIN && d <= WIN) ? val : -INFINITY;
            }
    }

    float mrow[2][4];
#pragma unroll
    for (int mt = 0; mt < 2; ++mt)
#pragma unroll
        for (int r = 0; r < 4; ++r) {
            float m = s[0][mt * 4 + r];
#pragma unroll
            for (int c = 1; c < NCHUNK; ++c) m = fmaxf(m, s[c][mt * 4 + r]);
            mrow[mt][r] = m;
        }
#pragma unroll
    for (int off = 1; off < 16; off <<= 1)
#pragma unroll
        for (int mt = 0; mt < 2; ++mt)
#pragma unroll
            for (int r = 0; r < 4; ++r)
                mrow[mt][r] = fmaxf(mrow[mt][r], __shfl_xor(mrow[mt][r], off));
    if (c16 == 0) {
#pragma unroll
        for (int mt = 0; mt < 2; ++mt)
#pragma unroll
            for (int r = 0; r < 4; ++r)
                stats0[(mt * 16 + rq + r) * 4 + w] = mrow[mt][r];
    }
    __syncthreads();
#pragma unroll
    for (int mt = 0; mt < 2; ++mt)
#pragma unroll
        for (int r = 0; r < 4; ++r) {
            const f32x4 q4 = *(const f32x4*)&stats0[(mt * 16 + rq + r) * 4];
            mrow[mt][r] = fmaxf(fmaxf(q4[0], q4[1]), fmaxf(q4[2], q4[3]));
        }
    float srow_[2][4];
#pragma unroll
    for (int mt = 0; mt < 2; ++mt)
#pragma unroll
        for (int r = 0; r < 4; ++r) srow_[mt][r] = 0.f;
#pragma unroll
    for (int c = 0; c < NCHUNK; ++c)
#pragma unroll
        for (int mt = 0; mt < 2; ++mt)
#pragma unroll
            for (int r = 0; r < 4; ++r) {
                const float e = __expf(s[c][mt * 4 + r] - mrow[mt][r]);
                s[c][mt * 4 + r] = e;
                srow_[mt][r] += e;
            }
#pragma unroll
    for (int off = 1; off < 16; off <<= 1)
#pragma unroll
        for (int mt = 0; mt < 2; ++mt)
#pragma unroll
            for (int r = 0; r < 4; ++r)
                srow_[mt][r] += __shfl_xor(srow_[mt][r], off);
    if (c16 == 0) {
#pragma unroll
        for (int mt = 0; mt < 2; ++mt)
#pragma unroll
            for (int r = 0; r < 4; ++r)
                stats1[(mt * 16 + rq + r) * 4 + w] = srow_[mt][r];
    }
    __syncthreads();
    float inv[2][4];
#pragma unroll
    for (int mt = 0; mt < 2; ++mt)
#pragma unroll
        for (int r = 0; r < 4; ++r) {
            const f32x4 q4 = *(const f32x4*)&stats1[(mt * 16 + rq + r) * 4];
            inv[mt][r] = 1.0f / (q4[0] + q4[1] + q4[2] + q4[3]);
        }

    u16x8 vpre[2][2];
#pragma unroll
    for (int ii = 0; ii < 2; ++ii) {
        const size_t g = (size_t)(jbase + ii * 32 + srow) * DKK + spart;
        vpre[ii][0] = *(const u16x8*)&vhp[g];
        vpre[ii][1] = *(const u16x8*)&vlp[g];
    }

    f32x4 oacc[2] = {};
#pragma unroll
    for (int c = 0; c < NCHUNK; ++c) {
        if (c > 0) __syncthreads();
#pragma unroll
        for (int mt = 0; mt < 2; ++mt)
#pragma unroll
            for (int r = 0; r < 4; ++r) {
                const int i = mt * 16 + rq + r;
                const float p = s[c][mt * 4 + r] * inv[mt][r];
                arow[(size_t)i * TT + jbase + c * 64 + wnq + c16] = p;
                const ushort_t ph = f2bf(p);
                const int col = (wnq + c16) ^ (((i >> 3) & 7) << 3);
                sA0[i * ALS + col] = ph;
                sA1[i * ALS + col] = f2bf(p - bf2f(ph));
            }
#pragma unroll
        for (int ii = 0; ii < 2; ++ii) {
            const int jr = ii * 32 + srow;
#pragma unroll
            for (int e = 0; e < 8; ++e) {
                const int dk = spart + e;
                const int idx = dk * ALS + (jr ^ (((dk >> 3) & 7) << 3));
                sB0[idx] = vpre[ii][0][e];
                sB1[idx] = vpre[ii][1][e];
            }
        }
        if (c + 1 < NCHUNK) {
#pragma unroll
            for (int ii = 0; ii < 2; ++ii) {
                const size_t g = (size_t)(jbase + (c + 1) * 64 + ii * 32 + srow) * DKK + spart;
                vpre[ii][0] = *(const u16x8*)&vhp[g];
                vpre[ii][1] = *(const u16x8*)&vlp[g];
            }
        }
        __syncthreads();
#pragma unroll
        for (int kk = 0; kk < 2; ++kk) {
            const int ku = kk * 32 + quad * 8;
            const bf16x8 vbh = *(const bf16x8*)&sB0[swi(wnq + c16, ku)];
            const bf16x8 vbl = *(const bf16x8*)&sB1[swi(wnq + c16, ku)];
#pragma unroll
            for (int mt = 0; mt < 2; ++mt) {
                const bf16x8 pah = *(const bf16x8*)&sA0[swi(mt * 16 + c16, ku)];
                const bf16x8 pal = *(const bf16x8*)&sA1[swi(mt * 16 + c16, ku)];
                oacc[mt] = __builtin_amdgcn_mfma_f32_16x16x32_bf16(pah, vbh, oacc[mt], 0, 0, 0);
                oacc[mt] = __builtin_amdgcn_mfma_f32_16x16x32_bf16(pal, vbh, oacc[mt], 0, 0, 0);
                oacc[mt] = __builtin_amdgcn_mfma_f32_16x16x32_bf16(pah, vbl, oacc[mt], 0, 0, 0);
            }
        }
    }

#pragma unroll
    for (int mt = 0; mt < 2; ++mt)
#pragma unroll
        for (int r = 0; r < 4; ++r) {
            const float val = oacc[mt][r];
            const int i = mt * 16 + rq + r;
            const int dk = wnq + c16;
            const ushort_t hh2 = f2bf(val);
            const size_t off = (((size_t)b * TT + irow0 + i) * HH + h) * DKK + dk;
            cxh[off] = hh2;
            cxl[off] = f2bf(val - bf2f(hh2));
        }
}

extern "C" void kernel_launch(void* const* d_in, const int* in_sizes, int n_in,
                              void* d_out, int out_size, void* d_ws, size_t ws_size,
                              hipStream_t stream)
{
    const float* x    = (const float*)d_in[0];
    const float* Wqkv = (const float*)d_in[1];
    const float* bqkv = (const float*)d_in[2];
    const float* Wo   = (const float*)d_in[3];
    const float* bo   = (const float*)d_in[4];
    const float* rel  = (const float*)d_in[5];

    float* out  = (float*)d_out;
    float* attn = out + (size_t)BB * TT * DD;

    const size_t per = (size_t)BB * HH * TT * DKK;   // 8,388,608 elements
    ushort_t* qh = (ushort_t*)d_ws;
    ushort_t* ql = qh + per;
    ushort_t* kh = ql + per;
    ushort_t* kl = kh + per;
    ushort_t* vh = kl + per;
    ushort_t* vl = vh + per;
    ushort_t* xh = vl + per;
    ushort_t* xl = xh + per;
    ushort_t* Wqh = xl + per;
    ushort_t* Wql = Wqh + (size_t)DD * 3 * DD;
    ushort_t* cxh = xh;                      // aliases xh (dead after qkv_mfma)
    ushort_t* cxl = xl;                      // aliases xl (dead after qkv_mfma)
    ushort_t* Woh = vh;                      // aliases vh (dead after attn)
    ushort_t* Wol = Woh + (size_t)DD * DD;

    const int n4x = BB * TT * DD / 4;        // 2,097,152

    conv_split<<<dim3((n4x + 255) / 256), 256, 0, stream>>>(x, xh, xl, n4x);
    conv_split_T<<<dim3(3 * DD / 32, DD / 32), 256, 0, stream>>>(Wqkv, Wqh, Wql, DD, 3 * DD);
    qkv_mfma<<<dim3(1536), 256, 0, stream>>>(xh, xl, Wqh, Wql, bqkv, qh, ql, kh, kl, vh, vl);
    attn_fused<<<dim3(4096), 256, 0, stream>>>(qh, ql, kh, kl, vh, vl, rel, attn, cxh, cxl);
    conv_split_T<<<dim3(DD / 32, DD / 32), 256, 0, stream>>>(Wo, Woh, Wol, DD, DD);
    out_mfma<<<dim3(512), 256, 0, stream>>>(cxh, cxl, Woh, Wol, bo, out);
}

// Round 7
// 544.531 us; speedup vs baseline: 1.5348x; 1.1491x over previous
//
#include <hip/hip_runtime.h>
#include <math.h>

typedef _Float16 half_t;
typedef _Float16 f16x8 __attribute__((ext_vector_type(8)));
typedef _Float16 f16x4 __attribute__((ext_vector_type(4)));
typedef float f32x4 __attribute__((ext_vector_type(4)));

#define BB 16
#define TT 512
#define DD 1024
#define HH 16
#define DKK 64
#define WIN 128
#define MAXLEN 512

#define TILE_M 64
#define JSPAN 320
#define NCHUNK 5

#define BK 32                 // GEMM K-step in halves; LDS rows 64B, linear
#define TBUF (128 * BK)       // halves per tensor per buffer
#define BUFU (3 * TBUF)       // halves per buffer (3 tensors: Ah, Al, B)
#define KSTEPS (DD / BK)      // 32

#define ALS 72                // attn LDS row stride in halves (144B: b128-aligned, rows 4 banks apart)

// async global->LDS, 16B per lane, wave-uniform LDS base + lane*16
#define GLOAD16(g, l)                                                                              \
    __builtin_amdgcn_global_load_lds((const __attribute__((address_space(1))) unsigned int*)(g),   \
                                     (__attribute__((address_space(3))) unsigned int*)(l), 16, 0, 0)

// ---------------- fp32 -> fp16 hi/lo split: hi = rtn(f), lo = rtn(f - hi)  (22-bit mantissa) ----
__device__ __forceinline__ half_t f2h(float f) { return (half_t)f; }
__device__ __forceinline__ float  h2f(half_t h) { return (float)h; }

// attn LDS index: row-stride 72 halves + XOR of (row>>3) onto the 16B slot.
// Applied identically on every write and read of the same tile (both-sides rule).
__device__ __forceinline__ int swi(int row, int col) {
    return row * ALS + (col ^ (((row >> 3) & 7) << 3));
}

// ---------------- conversion: A [M][K] fp32 -> hi/lo fp16 same layout ----------------
__global__ __launch_bounds__(256) void conv_split(const float* __restrict__ src,
                                                  half_t* __restrict__ hi,
                                                  half_t* __restrict__ lo, int n4)
{
    const int i = blockIdx.x * 256 + threadIdx.x;
    if (i >= n4) return;
    float4 vf = ((const float4*)src)[i];
    float vv[4] = {vf.x, vf.y, vf.z, vf.w};
    f16x4 hv, lv;
#pragma unroll
    for (int j = 0; j < 4; ++j) {
        const half_t h = f2h(vv[j]);
        hv[j] = h;
        lv[j] = f2h(vv[j] - h2f(h));
    }
    *(f16x4*)&hi[(size_t)i * 4] = hv;
    *(f16x4*)&lo[(size_t)i * 4] = lv;
}

// ---------------- conversion + transpose: W [K][N] fp32 -> [N][K] single fp16 ----------------
__global__ __launch_bounds__(256) void conv_T(const float* __restrict__ W,
                                              half_t* __restrict__ hiT,
                                              int K, int N)
{
    __shared__ half_t th[32][33];
    const int n0 = blockIdx.x * 32, k0 = blockIdx.y * 32;
    const int tid = threadIdx.x;
    const int r = tid >> 3, c4 = (tid & 7) * 4;
    float4 vf = *(const float4*)&W[(size_t)(k0 + r) * N + n0 + c4];
    float vv[4] = {vf.x, vf.y, vf.z, vf.w};
#pragma unroll
    for (int j = 0; j < 4; ++j) th[r][c4 + j] = f2h(vv[j]);
    __syncthreads();
    f16x4 oh = {th[c4 + 0][r], th[c4 + 1][r], th[c4 + 2][r], th[c4 + 3][r]};
    *(f16x4*)&hiT[(size_t)(n0 + r) * K + k0 + c4] = oh;
}

// ---------------- 2-term fp16 split-A MFMA mainloop, 2-phase double-buffered ----------------
// C = (Ah + Al) * B : A is 22-bit (hi+lo fp16, exact-ish), B single fp16 (11-bit).
// 3 LDS streams, 6 global_load_lds per K-step, counted vmcnt(6). Swizzle per rule #21:
// linear LDS dest, inverse-swizzled global source, same XOR on ds_read (q' = q ^ ((row>>1)&3)).
// A-frag: lane holds A[m=lane&15][k=quad*8+j]; B-frag: B[k=quad*8+j][n=lane&15] (B stored [n][k]).
// C/D: col=lane&15, row=quad*4+reg  [verified m89/m91; layout dtype-independent]
__device__ __forceinline__ void mfma_mainloop(const half_t* __restrict__ Ah,
                                              const half_t* __restrict__ Al,
                                              const half_t* __restrict__ Bh,
                                              int m0, int n0,
                                              half_t* smem, f32x4 (&acc)[4][4])
{
    const int tid = threadIdx.x;
    const int lane = tid & 63;
    const int w = tid >> 6;
    const int wm = (w >> 1) * 64, wn = (w & 1) * 64;
    const int c16 = lane & 15;
    const int quad = lane >> 4;

    const int lrow = lane >> 2, lq = lane & 3;
    const int r0 = w * 32, r1 = w * 32 + 16;
    const int row0 = r0 + lrow, row1 = r1 + lrow;
    const int qd0 = lq ^ ((row0 >> 1) & 3);
    const int qd1 = lq ^ ((row1 >> 1) & 3);
    const size_t a0 = (size_t)(m0 + row0) * DD + qd0 * 8;
    const size_t a1 = (size_t)(m0 + row1) * DD + qd1 * 8;
    const size_t b0 = (size_t)(n0 + row0) * DD + qd0 * 8;
    const size_t b1 = (size_t)(n0 + row1) * DD + qd1 * 8;

    auto STAGE = [&](int buf, int k0) {
        half_t* s_ = smem + buf * BUFU;
        GLOAD16(Ah + a0 + k0, (char*)s_ + r0 * 64);
        GLOAD16(Ah + a1 + k0, (char*)s_ + r1 * 64);
        GLOAD16(Al + a0 + k0, (char*)(s_ + TBUF) + r0 * 64);
        GLOAD16(Al + a1 + k0, (char*)(s_ + TBUF) + r1 * 64);
        GLOAD16(Bh + b0 + k0, (char*)(s_ + 2 * TBUF) + r0 * 64);
        GLOAD16(Bh + b1 + k0, (char*)(s_ + 2 * TBUF) + r1 * 64);
    };

    int aoff[4], boff[4];
#pragma unroll
    for (int mt = 0; mt < 4; ++mt) {
        const int row = wm + mt * 16 + c16;
        aoff[mt] = row * BK + ((quad ^ ((row >> 1) & 3)) * 8);
    }
#pragma unroll
    for (int nt = 0; nt < 4; ++nt) {
        const int row = wn + nt * 16 + c16;
        boff[nt] = row * BK + ((quad ^ ((row >> 1) & 3)) * 8);
    }

    STAGE(0, 0);
    for (int t = 0; t < KSTEPS; ++t) {
        const int cur = t & 1;
        if (t + 1 < KSTEPS) {
            STAGE(cur ^ 1, (t + 1) * BK);
            asm volatile("s_waitcnt vmcnt(6)" ::: "memory");   // tile t's 6 loads done; next 6 in flight
        } else {
            asm volatile("s_waitcnt vmcnt(0)" ::: "memory");
        }
        __builtin_amdgcn_sched_barrier(0);
        __builtin_amdgcn_s_barrier();

        const half_t* sAh = smem + cur * BUFU;
        const half_t* sAl = sAh + TBUF;
        const half_t* sBh = sAh + 2 * TBUF;
        f16x8 ah[4], al[4];
#pragma unroll
        for (int mt = 0; mt < 4; ++mt) {
            ah[mt] = *(const f16x8*)&sAh[aoff[mt]];
            al[mt] = *(const f16x8*)&sAl[aoff[mt]];
        }
#pragma unroll
        for (int nt = 0; nt < 4; ++nt) {
            f16x8 bh = *(const f16x8*)&sBh[boff[nt]];
#pragma unroll
            for (int mt = 0; mt < 4; ++mt) {
                acc[mt][nt] = __builtin_amdgcn_mfma_f32_16x16x32_f16(ah[mt], bh, acc[mt][nt], 0, 0, 0);
                acc[mt][nt] = __builtin_amdgcn_mfma_f32_16x16x32_f16(al[mt], bh, acc[mt][nt], 0, 0, 0);
            }
        }
        __builtin_amdgcn_sched_barrier(0);
        __builtin_amdgcn_s_barrier();
    }
}

// ---------------- GEMM 1: qkv -> q split (hi/lo), k single, v single fp16 [B,H,T,DK] ----------------
__global__ __launch_bounds__(256) void qkv_mfma(const half_t* __restrict__ xh,
                                                const half_t* __restrict__ xl,
                                                const half_t* __restrict__ wh,
                                                const float* __restrict__ bias,
                                                half_t* __restrict__ qh,
                                                half_t* __restrict__ ql,
                                                half_t* __restrict__ kh,
                                                half_t* __restrict__ vh)
{
    __shared__ half_t smem[2 * BUFU];                // 48 KiB
    f32x4 acc[4][4] = {};
    const int bid = blockIdx.x;
    const int swz = (bid & 7) * 192 + (bid >> 3);    // nwg=1536, cpx=192
    const int n0 = (swz % 24) * 128;
    const int m0 = (swz / 24) * 128;
    mfma_mainloop(xh, xl, wh, m0, n0, smem, acc);

    const int tid = threadIdx.x, lane = tid & 63, w = tid >> 6;
    const int wm = (w >> 1) * 64, wn = (w & 1) * 64;
    const int c16 = lane & 15, rq = (lane >> 4) * 4;
#pragma unroll
    for (int mt = 0; mt < 4; ++mt)
#pragma unroll
        for (int nt = 0; nt < 4; ++nt)
#pragma unroll
            for (int r = 0; r < 4; ++r) {
                const int m = m0 + wm + mt * 16 + rq + r;
                const int n = n0 + wn + nt * 16 + c16;
                const float val = acc[mt][nt][r] + bias[n];
                const int bidx = m >> 9, t = m & (TT - 1);
                const int sel = n >> 10, d = n & (DD - 1);
                const int hd = d >> 6, dk = d & (DKK - 1);
                const size_t base = ((((size_t)bidx * HH + hd) * TT + t) * DKK) + dk;
                const half_t hv = f2h(val);
                if (sel == 0) {
                    qh[base] = hv;
                    ql[base] = f2h(val - h2f(hv));
                } else if (sel == 1) {
                    kh[base] = hv;
                } else {
                    vh[base] = hv;
                }
            }
}

// ---------------- GEMM 2: out = ctx @ Wo + bo ----------------
__global__ __launch_bounds__(256) void out_mfma(const half_t* __restrict__ ah,
                                                const half_t* __restrict__ al,
                                                const half_t* __restrict__ wh,
                                                const float* __restrict__ bias,
                                                float* __restrict__ out)
{
    __shared__ half_t smem[2 * BUFU];                // 48 KiB
    f32x4 acc[4][4] = {};
    const int bid = blockIdx.x;
    const int swz = (bid & 7) * 64 + (bid >> 3);     // nwg=512, cpx=64
    const int n0 = (swz & 7) * 128;
    const int m0 = (swz >> 3) * 128;
    mfma_mainloop(ah, al, wh, m0, n0, smem, acc);

    const int tid = threadIdx.x, lane = tid & 63, w = tid >> 6;
    const int wm = (w >> 1) * 64, wn = (w & 1) * 64;
    const int c16 = lane & 15, rq = (lane >> 4) * 4;
#pragma unroll
    for (int mt = 0; mt < 4; ++mt)
#pragma unroll
        for (int nt = 0; nt < 4; ++nt)
#pragma unroll
            for (int r = 0; r < 4; ++r) {
                const int m = m0 + wm + mt * 16 + rq + r;
                const int n = n0 + wn + nt * 16 + c16;
                out[(size_t)m * DD + n] = acc[mt][nt][r] + bias[n];
            }
}

// ---------------- Fused windowed attention: 4-wave blocks, 32 q-rows, fp16 2-term/1-term ----
// QK^T: Q split (qh+ql, 2 MFMAs), K single. PV: P single fp16 (1 MFMA), V single.
// All score state in registers with compile-time indices. LDS ~21 KB.
__global__ __launch_bounds__(256) void attn_fused(const half_t* __restrict__ qh_g,
                                                  const half_t* __restrict__ ql_g,
                                                  const half_t* __restrict__ kh_g,
                                                  const half_t* __restrict__ vh_g,
                                                  const float* __restrict__ rel,
                                                  float* __restrict__ attn_out,
                                                  half_t* __restrict__ cxh,
                                                  half_t* __restrict__ cxl)
{
    const int gid = blockIdx.x;
    const int x = gid & 7;
    const int v = (gid >> 3) & 15;
    const int u = gid >> 7;
    const int it = v >> 1, mh = v & 1;
    const int bh_idx = u * 8 + x;
    const int h = bh_idx & 15, b = bh_idx >> 4;
    const int i0 = it * TILE_M;
    int jbase = i0 - WIN; if (jbase < 0) jbase = 0; if (jbase > TT - JSPAN) jbase = TT - JSPAN;
    const int irow0 = i0 + mh * 32;

    const int tid = threadIdx.x;
    const int lane = tid & 63, w = tid >> 6;
    const int c16 = lane & 15, quad = lane >> 4, rq = quad * 4;
    const int wnq = w * 16;

    __shared__ half_t sA0[32 * ALS], sA1[32 * ALS];     // Qh/Ql, then P(single, sA0)
    __shared__ half_t sB0[64 * ALS];                    // K chunk, then V^T chunk
    __shared__ float bias_s[260];
    __shared__ float stats0[128], stats1[128];

    const size_t bh = (size_t)b * HH + h;
    const half_t* qhp = qh_g + (bh * TT + irow0) * DKK;
    const half_t* qlp = ql_g + (bh * TT + irow0) * DKK;
    const half_t* khp = kh_g + bh * TT * DKK;
    const half_t* vhp = vh_g + bh * TT * DKK;
    float* arow = attn_out + (bh * TT + irow0) * TT;

    const int srow = tid >> 3, spart = (tid & 7) * 8;

    // T14: K chunk-0 prefetch first
    f16x8 kpre[2];
#pragma unroll
    for (int ii = 0; ii < 2; ++ii)
        kpre[ii] = *(const f16x8*)&khp[(size_t)(jbase + ii * 32 + srow) * DKK + spart];

    {
        const float4 z = make_float4(0.f, 0.f, 0.f, 0.f);
        for (int idx = tid; idx < 32 * 48; idx += 256) {
            const int r  = idx / 48;
            const int c4 = idx - r * 48;
            const int col = (c4 * 4 < jbase) ? c4 * 4 : c4 * 4 + JSPAN;
            *(float4*)&arow[(size_t)r * TT + col] = z;
        }
    }
    if (tid < 257) bias_s[tid] = rel[(size_t)(tid + MAXLEN - 1 - 128) * HH + h];

    *(f16x8*)&sA0[swi(srow, spart)] = *(const f16x8*)&qhp[(size_t)srow * DKK + spart];
    *(f16x8*)&sA1[swi(srow, spart)] = *(const f16x8*)&qlp[(size_t)srow * DKK + spart];

    float s[NCHUNK][8];                 // [chunk][mt*4+r], all static indices
#pragma unroll
    for (int c = 0; c < NCHUNK; ++c) {
#pragma unroll
        for (int ii = 0; ii < 2; ++ii)
            *(f16x8*)&sB0[swi(ii * 32 + srow, spart)] = kpre[ii];
        if (c + 1 < NCHUNK) {
#pragma unroll
            for (int ii = 0; ii < 2; ++ii)
                kpre[ii] = *(const f16x8*)&khp[(size_t)(jbase + (c + 1) * 64 + ii * 32 + srow) * DKK + spart];
        }
        __syncthreads();
        f32x4 sacc[2] = {};
#pragma unroll
        for (int kk = 0; kk < 2; ++kk) {
            const int ku = kk * 32 + quad * 8;
            const f16x8 kb = *(const f16x8*)&sB0[swi(wnq + c16, ku)];
#pragma unroll
            for (int mt = 0; mt < 2; ++mt) {
                const f16x8 qah = *(const f16x8*)&sA0[swi(mt * 16 + c16, ku)];
                const f16x8 qal = *(const f16x8*)&sA1[swi(mt * 16 + c16, ku)];
                sacc[mt] = __builtin_amdgcn_mfma_f32_16x16x32_f16(qah, kb, sacc[mt], 0, 0, 0);
                sacc[mt] = __builtin_amdgcn_mfma_f32_16x16x32_f16(qal, kb, sacc[mt], 0, 0, 0);
            }
        }
        __syncthreads();
#pragma unroll
        for (int mt = 0; mt < 2; ++mt)
#pragma unroll
            for (int r = 0; r < 4; ++r) {
                const int i = irow0 + mt * 16 + rq + r;
                const int j = jbase + c * 64 + wnq + c16;
                const int d = j - i;
                const int bi = (d < -128) ? -128 : (d > 128 ? 128 : d);
                const float val = sacc[mt][r] * 0.125f + bias_s[bi + 128];
                s[c][mt * 4 + r] = (d >= -WIN && d <= WIN) ? val : -INFINITY;
            }
    }

    float mrow[2][4];
#pragma unroll
    for (int mt = 0; mt < 2; ++mt)
#pragma unroll
        for (int r = 0; r < 4; ++r) {
            float m = s[0][mt * 4 + r];
#pragma unroll
            for (int c = 1; c < NCHUNK; ++c) m = fmaxf(m, s[c][mt * 4 + r]);
            mrow[mt][r] = m;
        }
#pragma unroll
    for (int off = 1; off < 16; off <<= 1)
#pragma unroll
        for (int mt = 0; mt < 2; ++mt)
#pragma unroll
            for (int r = 0; r < 4; ++r)
                mrow[mt][r] = fmaxf(mrow[mt][r], __shfl_xor(mrow[mt][r], off));
    if (c16 == 0) {
#pragma unroll
        for (int mt = 0; mt < 2; ++mt)
#pragma unroll
            for (int r = 0; r < 4; ++r)
                stats0[(mt * 16 + rq + r) * 4 + w] = mrow[mt][r];
    }
    __syncthreads();
#pragma unroll
    for (int mt = 0; mt < 2; ++mt)
#pragma unroll
        for (int r = 0; r < 4; ++r) {
            const f32x4 q4 = *(const f32x4*)&stats0[(mt * 16 + rq + r) * 4];
            mrow[mt][r] = fmaxf(fmaxf(q4[0], q4[1]), fmaxf(q4[2], q4[3]));
        }
    float srow_[2][4];
#pragma unroll
    for (int mt = 0; mt < 2; ++mt)
#pragma unroll
        for (int r = 0; r < 4; ++r) srow_[mt][r] = 0.f;
#pragma unroll
    for (int c = 0; c < NCHUNK; ++c)
#pragma unroll
        for (int mt = 0; mt < 2; ++mt)
#pragma unroll
            for (int r = 0; r < 4; ++r) {
                const float e = __expf(s[c][mt * 4 + r] - mrow[mt][r]);
                s[c][mt * 4 + r] = e;
                srow_[mt][r] += e;
            }
#pragma unroll
    for (int off = 1; off < 16; off <<= 1)
#pragma unroll
        for (int mt = 0; mt < 2; ++mt)
#pragma unroll
            for (int r = 0; r < 4; ++r)
                srow_[mt][r] += __shfl_xor(srow_[mt][r], off);
    if (c16 == 0) {
#pragma unroll
        for (int mt = 0; mt < 2; ++mt)
#pragma unroll
            for (int r = 0; r < 4; ++r)
                stats1[(mt * 16 + rq + r) * 4 + w] = srow_[mt][r];
    }
    __syncthreads();
    float inv[2][4];
#pragma unroll
    for (int mt = 0; mt < 2; ++mt)
#pragma unroll
        for (int r = 0; r < 4; ++r) {
            const f32x4 q4 = *(const f32x4*)&stats1[(mt * 16 + rq + r) * 4];
            inv[mt][r] = 1.0f / (q4[0] + q4[1] + q4[2] + q4[3]);
        }

    // T14: V chunk-0 prefetch
    f16x8 vpre[2];
#pragma unroll
    for (int ii = 0; ii < 2; ++ii)
        vpre[ii] = *(const f16x8*)&vhp[(size_t)(jbase + ii * 32 + srow) * DKK + spart];

    f32x4 oacc[2] = {};
#pragma unroll
    for (int c = 0; c < NCHUNK; ++c) {
        if (c > 0) __syncthreads();
        // P -> global (fp32) + LDS (single fp16, A-layout)
#pragma unroll
        for (int mt = 0; mt < 2; ++mt)
#pragma unroll
            for (int r = 0; r < 4; ++r) {
                const int i = mt * 16 + rq + r;
                const float p = s[c][mt * 4 + r] * inv[mt][r];
                arow[(size_t)i * TT + jbase + c * 64 + wnq + c16] = p;
                const int col = (wnq + c16) ^ (((i >> 3) & 7) << 3);
                sA0[i * ALS + col] = f2h(p);
            }
        // V^T scatter from prefetched regs: rows dk, cols j
#pragma unroll
        for (int ii = 0; ii < 2; ++ii) {
            const int jr = ii * 32 + srow;
#pragma unroll
            for (int e = 0; e < 8; ++e) {
                const int dk = spart + e;
                sB0[dk * ALS + (jr ^ (((dk >> 3) & 7) << 3))] = vpre[ii][e];
            }
        }
        if (c + 1 < NCHUNK) {
#pragma unroll
            for (int ii = 0; ii < 2; ++ii)
                vpre[ii] = *(const f16x8*)&vhp[(size_t)(jbase + (c + 1) * 64 + ii * 32 + srow) * DKK + spart];
        }
        __syncthreads();
#pragma unroll
        for (int kk = 0; kk < 2; ++kk) {
            const int ku = kk * 32 + quad * 8;
            const f16x8 vb = *(const f16x8*)&sB0[swi(wnq + c16, ku)];
#pragma unroll
            for (int mt = 0; mt < 2; ++mt) {
                const f16x8 pa = *(const f16x8*)&sA0[swi(mt * 16 + c16, ku)];
                oacc[mt] = __builtin_amdgcn_mfma_f32_16x16x32_f16(pa, vb, oacc[mt], 0, 0, 0);
            }
        }
    }

    // fused ctx -> fp16 hi/lo split epilogue ([B,T,H,DK] layout)
#pragma unroll
    for (int mt = 0; mt < 2; ++mt)
#pragma unroll
        for (int r = 0; r < 4; ++r) {
            const float val = oacc[mt][r];
            const int i = mt * 16 + rq + r;
            const int dk = wnq + c16;
            const half_t hv = f2h(val);
            const size_t off = (((size_t)b * TT + irow0 + i) * HH + h) * DKK + dk;
            cxh[off] = hv;
            cxl[off] = f2h(val - h2f(hv));
        }
}

extern "C" void kernel_launch(void* const* d_in, const int* in_sizes, int n_in,
                              void* d_out, int out_size, void* d_ws, size_t ws_size,
                              hipStream_t stream)
{
    const float* x    = (const float*)d_in[0];
    const float* Wqkv = (const float*)d_in[1];
    const float* bqkv = (const float*)d_in[2];
    const float* Wo   = (const float*)d_in[3];
    const float* bo   = (const float*)d_in[4];
    const float* rel  = (const float*)d_in[5];

    float* out  = (float*)d_out;
    float* attn = out + (size_t)BB * TT * DD;

    const size_t per = (size_t)BB * HH * TT * DKK;   // 8,388,608 elements
    half_t* qh = (half_t*)d_ws;
    half_t* ql = qh + per;
    half_t* kh = ql + per;
    half_t* vh = kh + per;
    half_t* xh = vh + per;
    half_t* xl = xh + per;
    half_t* Wqh = xl + per;                          // 3*DD*DD halves
    half_t* cxh = xh;                                // aliases xh (dead after qkv_mfma)
    half_t* cxl = xl;                                // aliases xl (dead after qkv_mfma)
    half_t* Woh = kh;                                // aliases kh (dead after attn)

    const int n4x = BB * TT * DD / 4;                // 2,097,152

    conv_split<<<dim3((n4x + 255) / 256), 256, 0, stream>>>(x, xh, xl, n4x);
    conv_T<<<dim3(3 * DD / 32, DD / 32), 256, 0, stream>>>(Wqkv, Wqh, DD, 3 * DD);
    qkv_mfma<<<dim3(1536), 256, 0, stream>>>(xh, xl, Wqh, bqkv, qh, ql, kh, vh);
    attn_fused<<<dim3(4096), 256, 0, stream>>>(qh, ql, kh, vh, rel, attn, cxh, cxl);
    conv_T<<<dim3(DD / 32, DD / 32), 256, 0, stream>>>(Wo, Woh, DD, DD);
    out_mfma<<<dim3(512), 256, 0, stream>>>(cxh, cxl, Woh, bo, out);
}